// Round 1
// baseline (21773.177 us; speedup 1.0000x reference)
//
#include <hip/hip_runtime.h>
#include <hip/hip_bf16.h>
#include <math.h>

#define MAXH 3
typedef unsigned int u32;

__device__ __forceinline__ float atomic_add_f(float* p, float v) {
    return __hip_atomic_fetch_add(p, v, __ATOMIC_RELAXED, __HIP_MEMORY_SCOPE_AGENT);
}
__device__ __forceinline__ float lrelu(float x) { return x > 0.0f ? x : 0.2f * x; }
// order-preserving float<->uint encoding for atomicMax
__device__ __forceinline__ u32 enc_f(float f) {
    u32 b = __float_as_uint(f);
    return (b & 0x80000000u) ? ~b : (b | 0x80000000u);
}
__device__ __forceinline__ float dec_f(u32 u) {
    return (u & 0x80000000u) ? __uint_as_float(u & 0x7fffffffu) : __uint_as_float(~u);
}

// ---------------- BFS hierarchy ----------------
__global__ void k_bfs_init(const int* __restrict__ seed_mask, int* reached, int* dist, int n) {
    int i = blockIdx.x * blockDim.x + threadIdx.x;
    if (i < n) {
        int r = (seed_mask[i] == 0);
        reached[i] = r;
        dist[i] = r ? 0 : (MAXH + 1);
    }
}
__global__ void k_bfs_edge(const int* __restrict__ src, const int* __restrict__ dst,
                           const int* __restrict__ reached, int* nbr, long long E) {
    long long e = blockIdx.x * (long long)blockDim.x + threadIdx.x;
    if (e < E) {
        if (reached[src[e]]) nbr[dst[e]] = 1;
    }
}
__global__ void k_bfs_node(int* reached, int* dist, const int* __restrict__ nbr, int h, int n) {
    int i = blockIdx.x * blockDim.x + threadIdx.x;
    if (i < n) {
        if (nbr[i] && !reached[i]) { dist[i] = h; reached[i] = 1; }
    }
}

// ---------------- GEMMs ----------------
// layer-1 special: A = [x (128) | onehot(dist) (4)]  @ W1 (132x64)
__global__ void k_gemm1(const float* __restrict__ x, const int* __restrict__ dist,
                        const float* __restrict__ W, float* __restrict__ out, int n) {
    __shared__ float sW[132 * 64];
    for (int i = threadIdx.x; i < 132 * 64; i += blockDim.x) sW[i] = W[i];
    __syncthreads();
    int r = blockIdx.x * 4 + (int)(threadIdx.x >> 6);
    int col = threadIdx.x & 63;
    if (r < n) {
        const float* xr = x + (size_t)r * 128;
        float acc = 0.0f;
#pragma unroll 8
        for (int k = 0; k < 128; k++) acc += xr[k] * sW[k * 64 + col];
        int d = dist[r];
        if (d <= MAXH) acc += sW[(128 + d) * 64 + col];
        out[(size_t)r * 64 + col] = acc;
    }
}

// generic: out(n,M) = A(n,K) @ W(K,M), W staged in LDS
__global__ void k_gemm(const float* __restrict__ A, const float* __restrict__ W,
                       float* __restrict__ out, int n, int K, int M) {
    extern __shared__ float sW[];
    for (int i = threadIdx.x; i < K * M; i += blockDim.x) sW[i] = W[i];
    __syncthreads();
    long long total = (long long)n * M;
    long long gid = blockIdx.x * (long long)blockDim.x + threadIdx.x;
    if (gid < total) {
        int row = (int)(gid / M);
        int col = (int)(gid % M);
        const float* ar = A + (size_t)row * K;
        float acc = 0.0f;
        for (int k = 0; k < K; k++) acc += ar[k] * sW[k * M + col];
        out[gid] = acc;
    }
}

// ---------------- attention logits ----------------
// als[i,h] = sum_c h[i,h,c]*a_src[h,c] ; ald likewise
__global__ void k_attn(const float* __restrict__ h, const float* __restrict__ a_s,
                       const float* __restrict__ a_d, float* als, float* ald,
                       int nH, int H, int C) {
    int i = blockIdx.x * blockDim.x + threadIdx.x;
    if (i < nH) {
        int hh = i % H;
        const float* hp = h + (size_t)i * C;
        float s = 0.0f, d = 0.0f;
        for (int c = 0; c < C; c++) {
            float v = hp[c];
            s += v * a_s[hh * C + c];
            d += v * a_d[hh * C + c];
        }
        als[i] = s;
        ald[i] = d;
    }
}

// ---------------- edge softmax: max pass ----------------
__global__ void k_max_init(const float* __restrict__ als, const float* __restrict__ ald,
                           u32* maxv, int nH) {
    int i = blockIdx.x * blockDim.x + threadIdx.x;
    if (i < nH) {
        float e = lrelu(als[i] + ald[i]);  // self-loop edge
        maxv[i] = enc_f(e);
    }
}
__global__ void k_max_edge(const int* __restrict__ src, const int* __restrict__ dst,
                           const float* __restrict__ als, const float* __restrict__ ald,
                           u32* maxv, long long E, int H) {
    long long e = blockIdx.x * (long long)blockDim.x + threadIdx.x;
    int hh = blockIdx.y;
    if (e < E) {
        int s = src[e], d = dst[e];
        float v = lrelu(als[(size_t)s * H + hh] + ald[(size_t)d * H + hh]);
        atomicMax(&maxv[(size_t)d * H + hh], enc_f(v));
    }
}

// ---------------- edge softmax: sum pass ----------------
__global__ void k_sum_init(const float* __restrict__ als, const float* __restrict__ ald,
                           const u32* __restrict__ maxv, float* denom, int nH) {
    int i = blockIdx.x * blockDim.x + threadIdx.x;
    if (i < nH) {
        float m = dec_f(maxv[i]);
        float e = lrelu(als[i] + ald[i]);
        denom[i] = expf(e - m);
    }
}
__global__ void k_sum_edge(const int* __restrict__ src, const int* __restrict__ dst,
                           const float* __restrict__ als, const float* __restrict__ ald,
                           const u32* __restrict__ maxv, float* denom, long long E, int H) {
    long long e = blockIdx.x * (long long)blockDim.x + threadIdx.x;
    int hh = blockIdx.y;
    if (e < E) {
        int s = src[e], d = dst[e];
        float v = lrelu(als[(size_t)s * H + hh] + ald[(size_t)d * H + hh]);
        float m = dec_f(maxv[(size_t)d * H + hh]);
        atomic_add_f(&denom[(size_t)d * H + hh], expf(v - m));
    }
}

// ---------------- edge softmax: aggregate pass ----------------
__global__ void k_agg_init(const float* __restrict__ h, const float* __restrict__ als,
                           const float* __restrict__ ald, const u32* __restrict__ maxv,
                           const float* __restrict__ denom, const float* __restrict__ bias,
                           float* out, long long total, int H, int C) {
    long long i = blockIdx.x * (long long)blockDim.x + threadIdx.x;
    if (i < total) {
        int c = (int)(i % C);
        long long ih = i / C;
        int hh = (int)(ih % H);
        float m = dec_f(maxv[ih]);
        float e = lrelu(als[ih] + ald[ih]);
        float alpha = expf(e - m) / (denom[ih] + 1e-16f);
        out[i] = h[i] * alpha + bias[hh * C + c];
    }
}
__global__ void k_agg_edge(const int* __restrict__ src, const int* __restrict__ dst,
                           const float* __restrict__ h, const float* __restrict__ als,
                           const float* __restrict__ ald, const u32* __restrict__ maxv,
                           const float* __restrict__ denom, float* out,
                           long long E, int H, int C) {
    long long e = blockIdx.x * (long long)blockDim.x + threadIdx.x;
    int hh = blockIdx.y;
    if (e < E) {
        int s = src[e], d = dst[e];
        float v = lrelu(als[(size_t)s * H + hh] + ald[(size_t)d * H + hh]);
        float m = dec_f(maxv[(size_t)d * H + hh]);
        float alpha = expf(v - m) / (denom[(size_t)d * H + hh] + 1e-16f);
        const float* hp = h + ((size_t)s * H + hh) * C;
        float* op = out + ((size_t)d * H + hh) * C;
        for (int c = 0; c < C; c++) atomic_add_f(&op[c], hp[c] * alpha);
    }
}

// ---------------- pointwise ----------------
__global__ void k_elu(float* p, long long tot) {
    long long i = blockIdx.x * (long long)blockDim.x + threadIdx.x;
    if (i < tot) {
        float v = p[i];
        p[i] = v > 0.0f ? v : expm1f(v);
    }
}

// gate: g = sigmoid(dot(h2_row, Wg[0:128]) + hop*Wg[128] + bg); h2_row *= g
__global__ void k_gate(float* h2, const int* __restrict__ dist, const float* __restrict__ Wg,
                       const float* __restrict__ bg, int n) {
    int node = blockIdx.x;
    int t = threadIdx.x;
    __shared__ float red[128];
    __shared__ float gate_s;
    float v = h2[(size_t)node * 128 + t] * Wg[t];
    red[t] = v;
    __syncthreads();
    for (int s = 64; s > 0; s >>= 1) {
        if (t < s) red[t] += red[t + s];
        __syncthreads();
    }
    if (t == 0) {
        int d = dist[node];
        float hop = (d <= MAXH) ? (float)d : 0.0f;
        float g = red[0] + hop * Wg[128] + bg[0];
        gate_s = 1.0f / (1.0f + expf(-g));
    }
    __syncthreads();
    h2[(size_t)node * 128 + t] *= gate_s;
}

// per-row log_softmax over C=40 (one wave per row)
__global__ void k_logsoftmax(float* out, int n, int C) {
    int node = blockIdx.x;
    int t = threadIdx.x;
    float v = (t < C) ? out[(size_t)node * C + t] : -INFINITY;
    float m = v;
    for (int o = 32; o > 0; o >>= 1) m = fmaxf(m, __shfl_xor(m, o));
    float e = (t < C) ? expf(v - m) : 0.0f;
    float s = e;
    for (int o = 32; o > 0; o >>= 1) s += __shfl_xor(s, o);
    float ls = logf(s);
    if (t < C) out[(size_t)node * C + t] = v - m - ls;
}

static inline int nblk(long long t, int b) { return (int)((t + b - 1) / b); }

extern "C" void kernel_launch(void* const* d_in, const int* in_sizes, int n_in,
                              void* d_out, int out_size, void* d_ws, size_t ws_size,
                              hipStream_t stream) {
    const float* x = (const float*)d_in[0];
    const int* eidx = (const int*)d_in[1];
    const int* seed_mask = (const int*)d_in[2];
    const float* W1 = (const float*)d_in[3];
    const float* a1s = (const float*)d_in[4];
    const float* a1d = (const float*)d_in[5];
    const float* b1 = (const float*)d_in[6];
    const float* W2 = (const float*)d_in[7];
    const float* a2s = (const float*)d_in[8];
    const float* a2d = (const float*)d_in[9];
    const float* b2 = (const float*)d_in[10];
    const float* W3 = (const float*)d_in[11];
    const float* a3s = (const float*)d_in[12];
    const float* a3d = (const float*)d_in[13];
    const float* b3 = (const float*)d_in[14];
    const float* Wg = (const float*)d_in[15];
    const float* bg = (const float*)d_in[16];

    const int n = in_sizes[0] / 128;        // 100000
    const long long E = in_sizes[1] / 2;    // 1600000
    const int* src = eidx;
    const int* dst = eidx + E;

    char* ws = (char*)d_ws;
    size_t off = 0;
    auto alloc = [&](size_t bytes) -> void* {
        void* p = ws + off;
        off = (off + bytes + 255) & ~(size_t)255;
        return p;
    };
    int* dist    = (int*)alloc((size_t)n * 4);
    int* reached = (int*)alloc((size_t)n * 4);
    int* nbr     = (int*)alloc((size_t)n * 4);
    float* als   = (float*)alloc((size_t)n * 8 * 4);
    float* ald   = (float*)alloc((size_t)n * 8 * 4);
    u32* maxv    = (u32*)alloc((size_t)n * 8 * 4);
    float* denom = (float*)alloc((size_t)n * 8 * 4);
    float* bufH  = (float*)alloc((size_t)n * 128 * 4);
    float* bufO  = (float*)alloc((size_t)n * 128 * 4);
    float* out = (float*)d_out;

    const int BS = 256;

    // ---- BFS hierarchy ----
    k_bfs_init<<<nblk(n, BS), BS, 0, stream>>>(seed_mask, reached, dist, n);
    for (int h = 1; h <= MAXH; h++) {
        hipMemsetAsync(nbr, 0, (size_t)n * 4, stream);
        k_bfs_edge<<<nblk(E, BS), BS, 0, stream>>>(src, dst, reached, nbr, E);
        k_bfs_node<<<nblk(n, BS), BS, 0, stream>>>(reached, dist, nbr, h, n);
    }

    auto gat = [&](const float* hbuf, const float* as_w, const float* ad_w,
                   const float* bias, float* obuf, int H, int C) {
        int nH = n * H;
        k_attn<<<nblk(nH, BS), BS, 0, stream>>>(hbuf, as_w, ad_w, als, ald, nH, H, C);
        k_max_init<<<nblk(nH, BS), BS, 0, stream>>>(als, ald, maxv, nH);
        dim3 ge((unsigned)nblk(E, BS), (unsigned)H);
        k_max_edge<<<ge, BS, 0, stream>>>(src, dst, als, ald, maxv, E, H);
        k_sum_init<<<nblk(nH, BS), BS, 0, stream>>>(als, ald, maxv, denom, nH);
        k_sum_edge<<<ge, BS, 0, stream>>>(src, dst, als, ald, maxv, denom, E, H);
        long long tot = (long long)n * H * C;
        k_agg_init<<<nblk(tot, BS), BS, 0, stream>>>(hbuf, als, ald, maxv, denom, bias, obuf,
                                                     tot, H, C);
        k_agg_edge<<<ge, BS, 0, stream>>>(src, dst, hbuf, als, ald, maxv, denom, obuf, E, H, C);
    };

    // ---- Layer 1: aug(132) -> 8 heads x 8 ----
    k_gemm1<<<nblk(n, 4), BS, 0, stream>>>(x, dist, W1, bufH, n);
    gat(bufH, a1s, a1d, b1, bufO, 8, 8);
    k_elu<<<nblk((long long)n * 64, BS), BS, 0, stream>>>(bufO, (long long)n * 64);

    // ---- Layer 2: 64 -> 8 heads x 16 ----
    k_gemm<<<nblk((long long)n * 128, BS), BS, 64 * 128 * 4, stream>>>(bufO, W2, bufH, n, 64, 128);
    gat(bufH, a2s, a2d, b2, bufO, 8, 16);

    // ---- gate ----
    k_gate<<<n, 128, 0, stream>>>(bufO, dist, Wg, bg, n);

    // ---- Layer 3: 128 -> 1 head x 40, into d_out ----
    k_gemm<<<nblk((long long)n * 40, BS), BS, 128 * 40 * 4, stream>>>(bufO, W3, bufH, n, 128, 40);
    gat(bufH, a3s, a3d, b3, out, 1, 40);

    // ---- log_softmax ----
    k_logsoftmax<<<n, 64, 0, stream>>>(out, n, 40);
}

// Round 2
// 1652.866 us; speedup vs baseline: 13.1730x; 13.1730x over previous
//
#include <hip/hip_runtime.h>
#include <hip/hip_bf16.h>
#include <math.h>

#define MAXH 3
typedef unsigned int u32;

__device__ __forceinline__ float lrelu(float x) { return x > 0.0f ? x : 0.2f * x; }

// ---------------- BFS hierarchy ----------------
__global__ void k_bfs_init(const int* __restrict__ seed_mask, int* reached, int* dist, int n) {
    int i = blockIdx.x * blockDim.x + threadIdx.x;
    if (i < n) {
        int r = (seed_mask[i] == 0);
        reached[i] = r;
        dist[i] = r ? 0 : (MAXH + 1);
    }
}
__global__ void k_bfs_edge(const int* __restrict__ src, const int* __restrict__ dst,
                           const int* __restrict__ reached, int* nbr, long long E) {
    long long e = blockIdx.x * (long long)blockDim.x + threadIdx.x;
    if (e < E) {
        if (reached[src[e]]) nbr[dst[e]] = 1;
    }
}
__global__ void k_bfs_node(int* reached, int* dist, const int* __restrict__ nbr, int h, int n) {
    int i = blockIdx.x * blockDim.x + threadIdx.x;
    if (i < n) {
        if (nbr[i] && !reached[i]) { dist[i] = h; reached[i] = 1; }
    }
}

// ---------------- CSR build (counting sort by dst) ----------------
__global__ void k_count(const int* __restrict__ dst, int* counts, long long E) {
    long long e = blockIdx.x * (long long)blockDim.x + threadIdx.x;
    if (e < E) atomicAdd(&counts[dst[e]], 1);
}
// per-block inclusive scan (256 elems) -> tmp, block sums -> sums
__global__ void k_scan1(const int* __restrict__ counts, int* tmp, int* sums, int n) {
    __shared__ int sd[256];
    int t = threadIdx.x;
    int i = blockIdx.x * 256 + t;
    int v = (i < n) ? counts[i] : 0;
    sd[t] = v;
    __syncthreads();
    for (int off = 1; off < 256; off <<= 1) {
        int add = (t >= off) ? sd[t - off] : 0;
        __syncthreads();
        sd[t] += add;
        __syncthreads();
    }
    if (i < n) tmp[i] = sd[t];
    if (t == 255) sums[blockIdx.x] = sd[t];
}
// single-block exclusive scan of block sums (nb <= 512)
__global__ void k_scan2(const int* __restrict__ sums, int* boff, int nb) {
    __shared__ int sd[512];
    int t = threadIdx.x;
    int v = (t < nb) ? sums[t] : 0;
    sd[t] = v;
    __syncthreads();
    for (int off = 1; off < 512; off <<= 1) {
        int add = (t >= off) ? sd[t - off] : 0;
        __syncthreads();
        sd[t] += add;
        __syncthreads();
    }
    if (t < nb) boff[t] = sd[t] - v;  // exclusive
}
__global__ void k_scan3(const int* __restrict__ tmp, const int* __restrict__ boff,
                        int* rowptr, int n) {
    int i = blockIdx.x * blockDim.x + threadIdx.x;
    if (i < n) {
        rowptr[i + 1] = tmp[i] + boff[i >> 8];
        if (i == 0) rowptr[0] = 0;
    }
}
__global__ void k_copy(const int* __restrict__ a, int* b, int n) {
    int i = blockIdx.x * blockDim.x + threadIdx.x;
    if (i < n) b[i] = a[i];
}
__global__ void k_scatter(const int* __restrict__ src, const int* __restrict__ dst,
                          int* cur, int* csr_src, long long E) {
    long long e = blockIdx.x * (long long)blockDim.x + threadIdx.x;
    if (e < E) {
        int d = dst[e];
        int pos = atomicAdd(&cur[d], 1);
        csr_src[pos] = src[e];
    }
}

// ---------------- GEMMs ----------------
// layer-1 special: A = [x (128) | onehot(dist) (4)]  @ W1 (132x64)
__global__ void k_gemm1(const float* __restrict__ x, const int* __restrict__ dist,
                        const float* __restrict__ W, float* __restrict__ out, int n) {
    __shared__ float sW[132 * 64];
    for (int i = threadIdx.x; i < 132 * 64; i += blockDim.x) sW[i] = W[i];
    __syncthreads();
    int r = blockIdx.x * 4 + (int)(threadIdx.x >> 6);
    int col = threadIdx.x & 63;
    if (r < n) {
        const float* xr = x + (size_t)r * 128;
        float acc = 0.0f;
#pragma unroll 8
        for (int k = 0; k < 128; k++) acc += xr[k] * sW[k * 64 + col];
        int d = dist[r];
        if (d <= MAXH) acc += sW[(128 + d) * 64 + col];
        out[(size_t)r * 64 + col] = acc;
    }
}

// generic: out(n,M) = A(n,K) @ W(K,M), W staged in LDS
__global__ void k_gemm(const float* __restrict__ A, const float* __restrict__ W,
                       float* __restrict__ out, int n, int K, int M) {
    extern __shared__ float sW[];
    for (int i = threadIdx.x; i < K * M; i += blockDim.x) sW[i] = W[i];
    __syncthreads();
    long long total = (long long)n * M;
    long long gid = blockIdx.x * (long long)blockDim.x + threadIdx.x;
    if (gid < total) {
        int row = (int)(gid / M);
        int col = (int)(gid % M);
        const float* ar = A + (size_t)row * K;
        float acc = 0.0f;
        for (int k = 0; k < K; k++) acc += ar[k] * sW[k * M + col];
        out[gid] = acc;
    }
}

// ---------------- attention logits ----------------
__global__ void k_attn(const float* __restrict__ h, const float* __restrict__ a_s,
                       const float* __restrict__ a_d, float* als, float* ald,
                       int nH, int H, int C) {
    int i = blockIdx.x * blockDim.x + threadIdx.x;
    if (i < nH) {
        int hh = i % H;
        const float* hp = h + (size_t)i * C;
        float s = 0.0f, d = 0.0f;
        for (int c = 0; c < C; c++) {
            float v = hp[c];
            s += v * a_s[hh * C + c];
            d += v * a_d[hh * C + c];
        }
        als[i] = s;
        ald[i] = d;
    }
}

// ---------------- fused per-node GAT (edge softmax + aggregate + bias [+ELU]) --------
// one wave per dst node; 4 nodes per 256-thread block
template <int H, int C, bool ELU>
__global__ void k_gat_fused(const int* __restrict__ rowptr, const int* __restrict__ csr_src,
                            const float* __restrict__ h, const float* __restrict__ als,
                            const float* __restrict__ ald, const float* __restrict__ bias,
                            float* __restrict__ out, int n) {
    constexpr int TOT = H * C;
    constexpr int NI = (TOT + 63) / 64;
    __shared__ float smh[4][H];
    __shared__ float ssh[4][H];
    const int w = threadIdx.x >> 6;
    const int lane = threadIdx.x & 63;
    const int node = blockIdx.x * 4 + w;
    const bool valid = node < n;

    int beg = 0, deg = 0;
    const int hh = lane & (H - 1);
    float m = -INFINITY, s = 0.0f;
    if (valid) {
        beg = rowptr[node];
        deg = rowptr[node + 1] - beg;
        const float aldv = ald[(size_t)node * H + hh];
        for (int k = lane / H; k <= deg; k += 64 / H) {  // k==deg -> self loop
            int sN = (k < deg) ? csr_src[beg + k] : node;
            float v = lrelu(als[(size_t)sN * H + hh] + aldv);
            if (v > m) { s = s * __expf(m - v) + 1.0f; m = v; }
            else s += __expf(v - m);
        }
    }
    // merge per-head partials across lanes (lanes with equal lane%H)
    for (int off = H; off < 64; off <<= 1) {
        float mo = __shfl_xor(m, off);
        float so = __shfl_xor(s, off);
        float M = fmaxf(m, mo);
        s = (M == -INFINITY) ? 0.0f : (s * __expf(m - M) + so * __expf(mo - M));
        m = M;
    }
    if (valid && lane < H) { smh[w][lane] = m; ssh[w][lane] = s; }
    __syncthreads();

    if (!valid) return;

    // phase 2: aggregate. lanes cover H*C channels (NI regs each)
    float acc[NI];
    float mreg[NI], inv[NI], aldr[NI];
    int hidx[NI], cidx[NI];
#pragma unroll
    for (int q = 0; q < NI; q++) {
        int idx = lane + q * 64;
        acc[q] = 0.0f;
        hidx[q] = idx / C;
        cidx[q] = idx % C;
        bool act = idx < TOT;
        mreg[q] = act ? smh[w][hidx[q]] : 0.0f;
        inv[q] = act ? 1.0f / (ssh[w][hidx[q]] + 1e-16f) : 0.0f;
        aldr[q] = act ? ald[(size_t)node * H + hidx[q]] : 0.0f;
    }
    for (int e = 0; e <= deg; e++) {
        int sN = (e < deg) ? csr_src[beg + e] : node;
        const float* hrow = h + (size_t)sN * TOT;
        const float* alrow = als + (size_t)sN * H;
#pragma unroll
        for (int q = 0; q < NI; q++) {
            int idx = lane + q * 64;
            if (idx < TOT) {
                float v = lrelu(alrow[hidx[q]] + aldr[q]);
                float alpha = __expf(v - mreg[q]) * inv[q];
                acc[q] += alpha * hrow[idx];
            }
        }
    }
#pragma unroll
    for (int q = 0; q < NI; q++) {
        int idx = lane + q * 64;
        if (idx < TOT) {
            float v = acc[q] + bias[idx];
            if (ELU) v = v > 0.0f ? v : expm1f(v);
            out[(size_t)node * TOT + idx] = v;
        }
    }
}

// ---------------- gate ----------------
__global__ void k_gate(float* h2, const int* __restrict__ dist, const float* __restrict__ Wg,
                       const float* __restrict__ bg, int n) {
    int node = blockIdx.x;
    int t = threadIdx.x;
    __shared__ float red[128];
    __shared__ float gate_s;
    float v = h2[(size_t)node * 128 + t] * Wg[t];
    red[t] = v;
    __syncthreads();
    for (int s = 64; s > 0; s >>= 1) {
        if (t < s) red[t] += red[t + s];
        __syncthreads();
    }
    if (t == 0) {
        int d = dist[node];
        float hop = (d <= MAXH) ? (float)d : 0.0f;
        float g = red[0] + hop * Wg[128] + bg[0];
        gate_s = 1.0f / (1.0f + expf(-g));
    }
    __syncthreads();
    h2[(size_t)node * 128 + t] *= gate_s;
}

// per-row log_softmax over C=40 (one wave per row)
__global__ void k_logsoftmax(float* out, int n, int C) {
    int node = blockIdx.x;
    int t = threadIdx.x;
    float v = (t < C) ? out[(size_t)node * C + t] : -INFINITY;
    float m = v;
    for (int o = 32; o > 0; o >>= 1) m = fmaxf(m, __shfl_xor(m, o));
    float e = (t < C) ? expf(v - m) : 0.0f;
    float s = e;
    for (int o = 32; o > 0; o >>= 1) s += __shfl_xor(s, o);
    float ls = logf(s);
    if (t < C) out[(size_t)node * C + t] = v - m - ls;
}

static inline int nblk(long long t, int b) { return (int)((t + b - 1) / b); }

extern "C" void kernel_launch(void* const* d_in, const int* in_sizes, int n_in,
                              void* d_out, int out_size, void* d_ws, size_t ws_size,
                              hipStream_t stream) {
    const float* x = (const float*)d_in[0];
    const int* eidx = (const int*)d_in[1];
    const int* seed_mask = (const int*)d_in[2];
    const float* W1 = (const float*)d_in[3];
    const float* a1s = (const float*)d_in[4];
    const float* a1d = (const float*)d_in[5];
    const float* b1 = (const float*)d_in[6];
    const float* W2 = (const float*)d_in[7];
    const float* a2s = (const float*)d_in[8];
    const float* a2d = (const float*)d_in[9];
    const float* b2 = (const float*)d_in[10];
    const float* W3 = (const float*)d_in[11];
    const float* a3s = (const float*)d_in[12];
    const float* a3d = (const float*)d_in[13];
    const float* b3 = (const float*)d_in[14];
    const float* Wg = (const float*)d_in[15];
    const float* bg = (const float*)d_in[16];

    const int n = in_sizes[0] / 128;        // 100000
    const long long E = in_sizes[1] / 2;    // 1600000
    const int* src = eidx;
    const int* dst = eidx + E;

    char* ws = (char*)d_ws;
    size_t off = 0;
    auto alloc = [&](size_t bytes) -> void* {
        void* p = ws + off;
        off = (off + bytes + 255) & ~(size_t)255;
        return p;
    };
    int* dist   = (int*)alloc((size_t)n * 4);
    int* buf1   = (int*)alloc((size_t)n * 4);      // reached / counts / cur
    int* buf2   = (int*)alloc((size_t)n * 4);      // nbr / tmp(scan)
    int* rowptr = (int*)alloc((size_t)(n + 1) * 4);
    int* sums   = (int*)alloc(512 * 4);
    int* boff   = (int*)alloc(512 * 4);
    int* csr_src = (int*)alloc((size_t)E * 4);
    float* als  = (float*)alloc((size_t)n * 8 * 4);
    float* ald  = (float*)alloc((size_t)n * 8 * 4);
    float* bufH = (float*)alloc((size_t)n * 128 * 4);
    float* bufO = (float*)alloc((size_t)n * 128 * 4);
    float* out = (float*)d_out;

    const int BS = 256;
    const int nb_scan = nblk(n, 256);

    // ---- BFS hierarchy (uses buf1=reached, buf2=nbr) ----
    k_bfs_init<<<nblk(n, BS), BS, 0, stream>>>(seed_mask, buf1, dist, n);
    for (int h = 1; h <= MAXH; h++) {
        hipMemsetAsync(buf2, 0, (size_t)n * 4, stream);
        k_bfs_edge<<<nblk(E, BS), BS, 0, stream>>>(src, dst, buf1, buf2, E);
        k_bfs_node<<<nblk(n, BS), BS, 0, stream>>>(buf1, dist, buf2, h, n);
    }

    // ---- CSR build by dst (buf1=counts/cur, buf2=tmp) ----
    hipMemsetAsync(buf1, 0, (size_t)n * 4, stream);
    k_count<<<nblk(E, BS), BS, 0, stream>>>(dst, buf1, E);
    k_scan1<<<nb_scan, 256, 0, stream>>>(buf1, buf2, sums, n);
    k_scan2<<<1, 512, 0, stream>>>(sums, boff, nb_scan);
    k_scan3<<<nblk(n, BS), BS, 0, stream>>>(buf2, boff, rowptr, n);
    k_copy<<<nblk(n, BS), BS, 0, stream>>>(rowptr, buf1, n);  // cur = rowptr[0:n]
    k_scatter<<<nblk(E, BS), BS, 0, stream>>>(src, dst, buf1, csr_src, E);

    // ---- Layer 1: aug(132) -> 8 heads x 8, ELU fused ----
    k_gemm1<<<nblk(n, 4), BS, 0, stream>>>(x, dist, W1, bufH, n);
    k_attn<<<nblk(n * 8, BS), BS, 0, stream>>>(bufH, a1s, a1d, als, ald, n * 8, 8, 8);
    k_gat_fused<8, 8, true><<<nblk(n, 4), 256, 0, stream>>>(rowptr, csr_src, bufH, als, ald,
                                                            b1, bufO, n);

    // ---- Layer 2: 64 -> 8 heads x 16 ----
    k_gemm<<<nblk((long long)n * 128, BS), BS, 64 * 128 * 4, stream>>>(bufO, W2, bufH, n, 64, 128);
    k_attn<<<nblk(n * 8, BS), BS, 0, stream>>>(bufH, a2s, a2d, als, ald, n * 8, 8, 16);
    k_gat_fused<8, 16, false><<<nblk(n, 4), 256, 0, stream>>>(rowptr, csr_src, bufH, als, ald,
                                                              b2, bufO, n);

    // ---- gate ----
    k_gate<<<n, 128, 0, stream>>>(bufO, dist, Wg, bg, n);

    // ---- Layer 3: 128 -> 1 head x 40 ----
    k_gemm<<<nblk((long long)n * 40, BS), BS, 128 * 40 * 4, stream>>>(bufO, W3, bufH, n, 128, 40);
    k_attn<<<nblk(n * 1, BS), BS, 0, stream>>>(bufH, a3s, a3d, als, ald, n, 1, 40);
    k_gat_fused<1, 40, false><<<nblk(n, 4), 256, 0, stream>>>(rowptr, csr_src, bufH, als, ald,
                                                              b3, out, n);

    // ---- log_softmax ----
    k_logsoftmax<<<n, 64, 0, stream>>>(out, n, 40);
}

// Round 3
// 1174.135 us; speedup vs baseline: 18.5440x; 1.4077x over previous
//
#include <hip/hip_runtime.h>
#include <hip/hip_bf16.h>
#include <math.h>

#define MAXH 3
typedef unsigned int u32;
typedef unsigned char u8;

__device__ __forceinline__ float lrelu(float x) { return x > 0.0f ? x : 0.2f * x; }

// ---------------- BFS hierarchy (byte flags) ----------------
__global__ void k_bfs_init(const int* __restrict__ seed_mask, u8* reached, int* dist, int n) {
    int i = blockIdx.x * blockDim.x + threadIdx.x;
    if (i < n) {
        int r = (seed_mask[i] == 0);
        reached[i] = (u8)r;
        dist[i] = r ? 0 : (MAXH + 1);
    }
}
__global__ void k_bfs_edge(const int* __restrict__ src, const int* __restrict__ dst,
                           const u8* __restrict__ reached, u8* nbr, long long E) {
    long long e = blockIdx.x * (long long)blockDim.x + threadIdx.x;
    if (e < E) {
        if (reached[src[e]]) nbr[dst[e]] = 1;
    }
}
__global__ void k_bfs_node(u8* reached, int* dist, const u8* __restrict__ nbr, int h, int n) {
    int i = blockIdx.x * blockDim.x + threadIdx.x;
    if (i < n) {
        if (nbr[i] && !reached[i]) { dist[i] = h; reached[i] = 1; }
    }
}

// ---------------- CSR build (counting sort by dst) ----------------
__global__ void k_count(const int* __restrict__ dst, int* counts, long long E) {
    long long e = blockIdx.x * (long long)blockDim.x + threadIdx.x;
    if (e < E) atomicAdd(&counts[dst[e]], 1);
}
__global__ void k_scan1(const int* __restrict__ counts, int* tmp, int* sums, int n) {
    __shared__ int sd[256];
    int t = threadIdx.x;
    int i = blockIdx.x * 256 + t;
    int v = (i < n) ? counts[i] : 0;
    sd[t] = v;
    __syncthreads();
    for (int off = 1; off < 256; off <<= 1) {
        int add = (t >= off) ? sd[t - off] : 0;
        __syncthreads();
        sd[t] += add;
        __syncthreads();
    }
    if (i < n) tmp[i] = sd[t];
    if (t == 255) sums[blockIdx.x] = sd[t];
}
__global__ void k_scan2(const int* __restrict__ sums, int* boff, int nb) {
    __shared__ int sd[512];
    int t = threadIdx.x;
    int v = (t < nb) ? sums[t] : 0;
    sd[t] = v;
    __syncthreads();
    for (int off = 1; off < 512; off <<= 1) {
        int add = (t >= off) ? sd[t - off] : 0;
        __syncthreads();
        sd[t] += add;
        __syncthreads();
    }
    if (t < nb) boff[t] = sd[t] - v;  // exclusive
}
__global__ void k_scan3(const int* __restrict__ tmp, const int* __restrict__ boff,
                        int* rowptr, int n) {
    int i = blockIdx.x * blockDim.x + threadIdx.x;
    if (i < n) {
        rowptr[i + 1] = tmp[i] + boff[i >> 8];
        if (i == 0) rowptr[0] = 0;
    }
}
__global__ void k_copy(const int* __restrict__ a, int* b, int n) {
    int i = blockIdx.x * blockDim.x + threadIdx.x;
    if (i < n) b[i] = a[i];
}
__global__ void k_scatter(const int* __restrict__ src, const int* __restrict__ dst,
                          int* cur, int* csr_src, long long E) {
    long long e = blockIdx.x * (long long)blockDim.x + threadIdx.x;
    if (e < E) {
        int d = dst[e];
        int pos = atomicAdd(&cur[d], 1);
        csr_src[pos] = src[e];
    }
}

// ---------------- register-tiled GEMM ----------------
// out(n, MREAL) = A(n, K) @ W(K..KW, MREAL); W zero-padded to MP cols in LDS.
// 64 rows per block, 256 threads. COLT=MP/4 col-threads, each thread RPT rows x 4 cols.
// AUG: add one-hot(dist) rows K..K+3 of W (layer 1).
template <int K, int KW, int MP, int MREAL, bool AUG>
__launch_bounds__(256)
__global__ void k_gemm_t(const float* __restrict__ A, const float* __restrict__ W,
                         const int* __restrict__ dist, float* __restrict__ out, int n) {
    constexpr int COLT = MP / 4;
    constexpr int ROWT = 256 / COLT;
    constexpr int RPT = 64 / ROWT;
    constexpr int BK = 64;
    constexpr int SAP = BK + 4;  // pad to break bank aliasing on trow-strided reads
    __shared__ float sA[64 * SAP];
    __shared__ float sW[KW * MP];

    for (int i = threadIdx.x; i < KW * MP; i += 256) {
        int r = i / MP, c = i % MP;
        sW[i] = (c < MREAL) ? W[r * MREAL + c] : 0.0f;
    }
    const int tcol = threadIdx.x % COLT;
    const int trow = threadIdx.x / COLT;
    const int rowbase = blockIdx.x * 64;

    float4 acc[RPT];
#pragma unroll
    for (int r = 0; r < RPT; r++) acc[r] = float4{0.f, 0.f, 0.f, 0.f};

    for (int k0 = 0; k0 < K; k0 += BK) {
        __syncthreads();
        for (int i = threadIdx.x; i < 64 * (BK / 4); i += 256) {
            int r = i / (BK / 4), c4 = i % (BK / 4);
            int row = rowbase + r;
            float4 v = float4{0.f, 0.f, 0.f, 0.f};
            if (row < n) v = *(const float4*)&A[(size_t)row * K + k0 + c4 * 4];
            *(float4*)&sA[r * SAP + c4 * 4] = v;
        }
        __syncthreads();
#pragma unroll
        for (int k4 = 0; k4 < BK / 4; k4++) {
            float4 w0 = *(const float4*)&sW[(k0 + k4 * 4 + 0) * MP + tcol * 4];
            float4 w1 = *(const float4*)&sW[(k0 + k4 * 4 + 1) * MP + tcol * 4];
            float4 w2 = *(const float4*)&sW[(k0 + k4 * 4 + 2) * MP + tcol * 4];
            float4 w3 = *(const float4*)&sW[(k0 + k4 * 4 + 3) * MP + tcol * 4];
#pragma unroll
            for (int r = 0; r < RPT; r++) {
                float4 a = *(const float4*)&sA[(trow * RPT + r) * SAP + k4 * 4];
                acc[r].x += a.x * w0.x + a.y * w1.x + a.z * w2.x + a.w * w3.x;
                acc[r].y += a.x * w0.y + a.y * w1.y + a.z * w2.y + a.w * w3.y;
                acc[r].z += a.x * w0.z + a.y * w1.z + a.z * w2.z + a.w * w3.z;
                acc[r].w += a.x * w0.w + a.y * w1.w + a.z * w2.w + a.w * w3.w;
            }
        }
    }
#pragma unroll
    for (int r = 0; r < RPT; r++) {
        int row = rowbase + trow * RPT + r;
        if (row < n) {
            if (AUG) {
                int d = dist[row];
                if (d <= MAXH) {
                    float4 wd = *(const float4*)&sW[(K + d) * MP + tcol * 4];
                    acc[r].x += wd.x; acc[r].y += wd.y; acc[r].z += wd.z; acc[r].w += wd.w;
                }
            }
            if (tcol * 4 + 3 < MREAL)
                *(float4*)&out[(size_t)row * MREAL + tcol * 4] = acc[r];
        }
    }
}

// ---------------- attention logits (vectorized) ----------------
template <int H, int C>
__global__ void k_attn_t(const float* __restrict__ h, const float* __restrict__ a_s,
                         const float* __restrict__ a_d, float* als, float* ald, int n) {
    int i = blockIdx.x * blockDim.x + threadIdx.x;
    if (i < n * H) {
        int hh = i % H;
        const float4* hp = (const float4*)(h + (size_t)i * C);
        const float4* asp = (const float4*)(a_s + hh * C);
        const float4* adp = (const float4*)(a_d + hh * C);
        float s = 0.0f, d = 0.0f;
#pragma unroll
        for (int c = 0; c < C / 4; c++) {
            float4 v = hp[c], va = asp[c], vd = adp[c];
            s += v.x * va.x + v.y * va.y + v.z * va.z + v.w * va.w;
            d += v.x * vd.x + v.y * vd.y + v.z * vd.z + v.w * vd.w;
        }
        als[i] = s;
        ald[i] = d;
    }
}

// ---------------- fused per-node GAT: single-pass online softmax + aggregate --------
// MODE: 1=ELU, 2=gate(sigmoid dot)+scale, 3=log_softmax
template <int H, int C, int MODE>
__launch_bounds__(256)
__global__ void k_gat(const int* __restrict__ rowptr, const int* __restrict__ csr_src,
                      const float* __restrict__ h, const float* __restrict__ als,
                      const float* __restrict__ ald, const float* __restrict__ bias,
                      const int* __restrict__ dist, const float* __restrict__ Wg,
                      const float* __restrict__ bg, float* __restrict__ out, int n) {
    constexpr int TOT = H * C;
    constexpr int NI = (TOT + 63) / 64;
    const int lane = threadIdx.x & 63;
    const int node = blockIdx.x * 4 + (threadIdx.x >> 6);
    if (node >= n) return;

    const int beg = rowptr[node];
    const int deg = rowptr[node + 1] - beg;
    const float* aldn = ald + (size_t)node * H;

    float aldr[NI], m[NI], s[NI], acc[NI];
    int hidx[NI];
#pragma unroll
    for (int q = 0; q < NI; q++) {
        int idx = lane + q * 64;
        hidx[q] = (idx < TOT) ? idx / C : 0;
        aldr[q] = aldn[hidx[q]];
        m[q] = -1e30f; s[q] = 0.0f; acc[q] = 0.0f;
    }
    for (int e = 0; e <= deg; e++) {
        const int sN = (e < deg) ? csr_src[beg + e] : node;  // e==deg -> self loop
        const float* hrow = h + (size_t)sN * TOT;
        const float* alrow = als + (size_t)sN * H;
#pragma unroll
        for (int q = 0; q < NI; q++) {
            int idx = lane + q * 64;
            if (idx < TOT) {
                float v = lrelu(alrow[hidx[q]] + aldr[q]);
                float mn = fmaxf(m[q], v);
                float sc = __expf(m[q] - mn);
                float p = __expf(v - mn);
                s[q] = s[q] * sc + p;
                acc[q] = acc[q] * sc + p * hrow[idx];
                m[q] = mn;
            }
        }
    }
    float val[NI];
#pragma unroll
    for (int q = 0; q < NI; q++) {
        int idx = lane + q * 64;
        val[q] = (idx < TOT) ? acc[q] / (s[q] + 1e-16f) + bias[idx] : 0.0f;
    }

    if (MODE == 1) {  // ELU
#pragma unroll
        for (int q = 0; q < NI; q++) val[q] = val[q] > 0.0f ? val[q] : expm1f(val[q]);
    } else if (MODE == 2) {  // gate (TOT==128)
        float part = val[0] * Wg[lane] + val[1] * Wg[lane + 64];
#pragma unroll
        for (int off = 32; off > 0; off >>= 1) part += __shfl_xor(part, off);
        int d = dist[node];
        float hop = (d <= MAXH) ? (float)d : 0.0f;
        float g = 1.0f / (1.0f + __expf(-(part + hop * Wg[128] + bg[0])));
#pragma unroll
        for (int q = 0; q < NI; q++) val[q] *= g;
    } else if (MODE == 3) {  // log_softmax (TOT==40, NI==1)
        float v = (lane < TOT) ? val[0] : -INFINITY;
        float mm = v;
#pragma unroll
        for (int off = 32; off > 0; off >>= 1) mm = fmaxf(mm, __shfl_xor(mm, off));
        float ex = (lane < TOT) ? __expf(v - mm) : 0.0f;
        float ss = ex;
#pragma unroll
        for (int off = 32; off > 0; off >>= 1) ss += __shfl_xor(ss, off);
        val[0] = v - mm - logf(ss);
    }
#pragma unroll
    for (int q = 0; q < NI; q++) {
        int idx = lane + q * 64;
        if (idx < TOT) out[(size_t)node * TOT + idx] = val[q];
    }
}

static inline int nblk(long long t, int b) { return (int)((t + b - 1) / b); }

extern "C" void kernel_launch(void* const* d_in, const int* in_sizes, int n_in,
                              void* d_out, int out_size, void* d_ws, size_t ws_size,
                              hipStream_t stream) {
    const float* x = (const float*)d_in[0];
    const int* eidx = (const int*)d_in[1];
    const int* seed_mask = (const int*)d_in[2];
    const float* W1 = (const float*)d_in[3];
    const float* a1s = (const float*)d_in[4];
    const float* a1d = (const float*)d_in[5];
    const float* b1 = (const float*)d_in[6];
    const float* W2 = (const float*)d_in[7];
    const float* a2s = (const float*)d_in[8];
    const float* a2d = (const float*)d_in[9];
    const float* b2 = (const float*)d_in[10];
    const float* W3 = (const float*)d_in[11];
    const float* a3s = (const float*)d_in[12];
    const float* a3d = (const float*)d_in[13];
    const float* b3 = (const float*)d_in[14];
    const float* Wg = (const float*)d_in[15];
    const float* bg = (const float*)d_in[16];

    const int n = in_sizes[0] / 128;        // 100000
    const long long E = in_sizes[1] / 2;    // 1600000
    const int* src = eidx;
    const int* dst = eidx + E;

    char* ws = (char*)d_ws;
    size_t off = 0;
    auto alloc = [&](size_t bytes) -> void* {
        void* p = ws + off;
        off = (off + bytes + 255) & ~(size_t)255;
        return p;
    };
    int* dist    = (int*)alloc((size_t)n * 4);
    int* buf1    = (int*)alloc((size_t)n * 4);      // counts / cur
    int* buf2    = (int*)alloc((size_t)n * 4);      // tmp(scan)
    u8* reached  = (u8*)alloc((size_t)n);
    u8* nbr      = (u8*)alloc((size_t)n);
    int* rowptr  = (int*)alloc((size_t)(n + 1) * 4);
    int* sums    = (int*)alloc(512 * 4);
    int* boff    = (int*)alloc(512 * 4);
    int* csr_src = (int*)alloc((size_t)E * 4);
    float* als   = (float*)alloc((size_t)n * 8 * 4);
    float* ald   = (float*)alloc((size_t)n * 8 * 4);
    float* bufH  = (float*)alloc((size_t)n * 128 * 4);
    float* bufO  = (float*)alloc((size_t)n * 128 * 4);
    float* out = (float*)d_out;

    const int BS = 256;
    const int nb_scan = nblk(n, 256);

    // ---- BFS hierarchy ----
    k_bfs_init<<<nblk(n, BS), BS, 0, stream>>>(seed_mask, reached, dist, n);
    for (int h = 1; h <= MAXH; h++) {
        hipMemsetAsync(nbr, 0, (size_t)n, stream);
        k_bfs_edge<<<nblk(E, BS), BS, 0, stream>>>(src, dst, reached, nbr, E);
        k_bfs_node<<<nblk(n, BS), BS, 0, stream>>>(reached, dist, nbr, h, n);
    }

    // ---- CSR build by dst ----
    hipMemsetAsync(buf1, 0, (size_t)n * 4, stream);
    k_count<<<nblk(E, BS), BS, 0, stream>>>(dst, buf1, E);
    k_scan1<<<nb_scan, 256, 0, stream>>>(buf1, buf2, sums, n);
    k_scan2<<<1, 512, 0, stream>>>(sums, boff, nb_scan);
    k_scan3<<<nblk(n, BS), BS, 0, stream>>>(buf2, boff, rowptr, n);
    k_copy<<<nblk(n, BS), BS, 0, stream>>>(rowptr, buf1, n);
    k_scatter<<<nblk(E, BS), BS, 0, stream>>>(src, dst, buf1, csr_src, E);

    // ---- Layer 1: aug(132) -> 8x8, ELU fused ----
    k_gemm_t<128, 132, 64, 64, true><<<nblk(n, 64), 256, 0, stream>>>(x, W1, dist, bufH, n);
    k_attn_t<8, 8><<<nblk(n * 8, BS), BS, 0, stream>>>(bufH, a1s, a1d, als, ald, n);
    k_gat<8, 8, 1><<<nblk(n, 4), 256, 0, stream>>>(rowptr, csr_src, bufH, als, ald, b1,
                                                   nullptr, nullptr, nullptr, bufO, n);

    // ---- Layer 2: 64 -> 8x16, gate fused ----
    k_gemm_t<64, 64, 128, 128, false><<<nblk(n, 64), 256, 0, stream>>>(bufO, W2, nullptr, bufH, n);
    k_attn_t<8, 16><<<nblk(n * 8, BS), BS, 0, stream>>>(bufH, a2s, a2d, als, ald, n);
    k_gat<8, 16, 2><<<nblk(n, 4), 256, 0, stream>>>(rowptr, csr_src, bufH, als, ald, b2,
                                                    dist, Wg, bg, bufO, n);

    // ---- Layer 3: 128 -> 1x40, log_softmax fused ----
    k_gemm_t<128, 128, 64, 40, false><<<nblk(n, 64), 256, 0, stream>>>(bufO, W3, nullptr, bufH, n);
    k_attn_t<1, 40><<<nblk(n, BS), BS, 0, stream>>>(bufH, a3s, a3d, als, ald, n);
    k_gat<1, 40, 3><<<nblk(n, 4), 256, 0, stream>>>(rowptr, csr_src, bufH, als, ald, b3,
                                                    nullptr, nullptr, nullptr, out, n);
}

// Round 4
// 1004.450 us; speedup vs baseline: 21.6767x; 1.1689x over previous
//
#include <hip/hip_runtime.h>
#include <hip/hip_bf16.h>
#include <math.h>

#define MAXH 3
typedef unsigned int u32;
typedef unsigned char u8;

__device__ __forceinline__ float lrelu(float x) { return x > 0.0f ? x : 0.2f * x; }

// ---------------- BFS hierarchy (byte flags, int4 edge loads) ----------------
__global__ void k_bfs_init(const int* __restrict__ seed_mask, u8* reached, int* dist, int n) {
    int i = blockIdx.x * blockDim.x + threadIdx.x;
    if (i < n) {
        int r = (seed_mask[i] == 0);
        reached[i] = (u8)r;
        dist[i] = r ? 0 : (MAXH + 1);
    }
}
__global__ void k_bfs_edge(const int4* __restrict__ src4, const int4* __restrict__ dst4,
                           const u8* __restrict__ reached, u8* nbr, int E4) {
    int i = blockIdx.x * blockDim.x + threadIdx.x;
    if (i < E4) {
        int4 s = src4[i], d = dst4[i];
        if (reached[s.x]) nbr[d.x] = 1;
        if (reached[s.y]) nbr[d.y] = 1;
        if (reached[s.z]) nbr[d.z] = 1;
        if (reached[s.w]) nbr[d.w] = 1;
    }
}
__global__ void k_bfs_node(u8* reached, int* dist, const u8* __restrict__ nbr, int h, int n) {
    int i = blockIdx.x * blockDim.x + threadIdx.x;
    if (i < n) {
        if (nbr[i] && !reached[i]) { dist[i] = h; reached[i] = 1; }
    }
}

// ---------------- CSR build (counting sort by dst) ----------------
__global__ void k_count(const int4* __restrict__ dst4, int* counts, int E4) {
    int i = blockIdx.x * blockDim.x + threadIdx.x;
    if (i < E4) {
        int4 d = dst4[i];
        atomicAdd(&counts[d.x], 1);
        atomicAdd(&counts[d.y], 1);
        atomicAdd(&counts[d.z], 1);
        atomicAdd(&counts[d.w], 1);
    }
}
__global__ void k_scan1(const int* __restrict__ counts, int* tmp, int* sums, int n) {
    __shared__ int sd[256];
    int t = threadIdx.x;
    int i = blockIdx.x * 256 + t;
    int v = (i < n) ? counts[i] : 0;
    sd[t] = v;
    __syncthreads();
    for (int off = 1; off < 256; off <<= 1) {
        int add = (t >= off) ? sd[t - off] : 0;
        __syncthreads();
        sd[t] += add;
        __syncthreads();
    }
    if (i < n) tmp[i] = sd[t];
    if (t == 255) sums[blockIdx.x] = sd[t];
}
__global__ void k_scan2(const int* __restrict__ sums, int* boff, int nb) {
    __shared__ int sd[512];
    int t = threadIdx.x;
    int v = (t < nb) ? sums[t] : 0;
    sd[t] = v;
    __syncthreads();
    for (int off = 1; off < 512; off <<= 1) {
        int add = (t >= off) ? sd[t - off] : 0;
        __syncthreads();
        sd[t] += add;
        __syncthreads();
    }
    if (t < nb) boff[t] = sd[t] - v;  // exclusive
}
// rowptr[i+1] = inclusive sum; cur[i] = rowptr[i] (= incl - counts[i])
__global__ void k_scan3(const int* __restrict__ tmp, const int* __restrict__ boff,
                        int* counts_to_cur, int* rowptr, int n) {
    int i = blockIdx.x * blockDim.x + threadIdx.x;
    if (i < n) {
        int incl = tmp[i] + boff[i >> 8];
        rowptr[i + 1] = incl;
        counts_to_cur[i] = incl - counts_to_cur[i];
        if (i == 0) rowptr[0] = 0;
    }
}
__global__ void k_scatter(const int4* __restrict__ src4, const int4* __restrict__ dst4,
                          int* cur, int* csr_src, int E4) {
    int i = blockIdx.x * blockDim.x + threadIdx.x;
    if (i < E4) {
        int4 s = src4[i], d = dst4[i];
        int p;
        p = atomicAdd(&cur[d.x], 1); csr_src[p] = s.x;
        p = atomicAdd(&cur[d.y], 1); csr_src[p] = s.y;
        p = atomicAdd(&cur[d.z], 1); csr_src[p] = s.z;
        p = atomicAdd(&cur[d.w], 1); csr_src[p] = s.w;
    }
}

// ---------------- register-tiled GEMM (RPT fixed at 4, bounded unroll) ----------------
// out(n, MREAL) = A(n, K) @ W(K..KW, MREAL); W zero-padded to MP cols in LDS.
// THREADS = 4*MP so each thread computes 4 rows x 4 cols.
template <int K, int KW, int MP, int MREAL, bool AUG, int THREADS>
__launch_bounds__(THREADS)
__global__ void k_gemm_t(const float* __restrict__ A, const float* __restrict__ W,
                         const int* __restrict__ dist, float* __restrict__ out, int n) {
    constexpr int COLT = MP / 4;
    constexpr int ROWT = THREADS / COLT;
    constexpr int RPT = 64 / ROWT;  // = 4
    constexpr int BK = 64;
    constexpr int SAP = BK + 4;
    __shared__ float sA[64 * SAP];
    __shared__ float sW[KW * MP];

    for (int i = threadIdx.x; i < KW * MP; i += THREADS) {
        int r = i / MP, c = i % MP;
        sW[i] = (c < MREAL) ? W[r * MREAL + c] : 0.0f;
    }
    const int tcol = threadIdx.x % COLT;
    const int trow = threadIdx.x / COLT;
    const int rowbase = blockIdx.x * 64;

    float4 acc[RPT];
#pragma unroll
    for (int r = 0; r < RPT; r++) acc[r] = float4{0.f, 0.f, 0.f, 0.f};

    for (int k0 = 0; k0 < K; k0 += BK) {
        __syncthreads();
        for (int i = threadIdx.x; i < 64 * (BK / 4); i += THREADS) {
            int r = i / (BK / 4), c4 = i % (BK / 4);
            int row = rowbase + r;
            float4 v = float4{0.f, 0.f, 0.f, 0.f};
            if (row < n) v = *(const float4*)&A[(size_t)row * K + k0 + c4 * 4];
            *(float4*)&sA[r * SAP + c4 * 4] = v;
        }
        __syncthreads();
#pragma unroll 2
        for (int k4 = 0; k4 < BK / 4; k4++) {
            float4 w0 = *(const float4*)&sW[(k0 + k4 * 4 + 0) * MP + tcol * 4];
            float4 w1 = *(const float4*)&sW[(k0 + k4 * 4 + 1) * MP + tcol * 4];
            float4 w2 = *(const float4*)&sW[(k0 + k4 * 4 + 2) * MP + tcol * 4];
            float4 w3 = *(const float4*)&sW[(k0 + k4 * 4 + 3) * MP + tcol * 4];
#pragma unroll
            for (int r = 0; r < RPT; r++) {
                float4 a = *(const float4*)&sA[(trow * RPT + r) * SAP + k4 * 4];
                acc[r].x += a.x * w0.x + a.y * w1.x + a.z * w2.x + a.w * w3.x;
                acc[r].y += a.x * w0.y + a.y * w1.y + a.z * w2.y + a.w * w3.y;
                acc[r].z += a.x * w0.z + a.y * w1.z + a.z * w2.z + a.w * w3.z;
                acc[r].w += a.x * w0.w + a.y * w1.w + a.z * w2.w + a.w * w3.w;
            }
        }
    }
#pragma unroll
    for (int r = 0; r < RPT; r++) {
        int row = rowbase + trow * RPT + r;
        if (row < n) {
            if (AUG) {
                int d = dist[row];
                if (d <= MAXH) {
                    float4 wd = *(const float4*)&sW[(K + d) * MP + tcol * 4];
                    acc[r].x += wd.x; acc[r].y += wd.y; acc[r].z += wd.z; acc[r].w += wd.w;
                }
            }
            if (tcol * 4 + 3 < MREAL)
                *(float4*)&out[(size_t)row * MREAL + tcol * 4] = acc[r];
        }
    }
}

// ---------------- attention logits (vectorized) ----------------
template <int H, int C>
__global__ void k_attn_t(const float* __restrict__ h, const float* __restrict__ a_s,
                         const float* __restrict__ a_d, float* als, float* ald, int n) {
    int i = blockIdx.x * blockDim.x + threadIdx.x;
    if (i < n * H) {
        int hh = i % H;
        const float4* hp = (const float4*)(h + (size_t)i * C);
        const float4* asp = (const float4*)(a_s + hh * C);
        const float4* adp = (const float4*)(a_d + hh * C);
        float s = 0.0f, d = 0.0f;
#pragma unroll
        for (int c = 0; c < C / 4; c++) {
            float4 v = hp[c], va = asp[c], vd = adp[c];
            s += v.x * va.x + v.y * va.y + v.z * va.z + v.w * va.w;
            d += v.x * vd.x + v.y * vd.y + v.z * vd.z + v.w * vd.w;
        }
        als[i] = s;
        ald[i] = d;
    }
}

// ---------------- fused per-node GAT: two-phase, shuffle-broadcast alphas --------
// phase 1: lanes = ES edge-slots x H heads, online (m,s) + butterfly merge (als only)
// phase 2: every lane computes alpha for head lane%H, __shfl to channel lanes, 1 FMA/ch
// MODE: 1=ELU, 2=gate(sigmoid dot)+scale, 3=log_softmax
template <int H, int C, int MODE>
__launch_bounds__(256)
__global__ void k_gat(const int* __restrict__ rowptr, const int* __restrict__ csr_src,
                      const float* __restrict__ h, const float* __restrict__ als,
                      const float* __restrict__ ald, const float* __restrict__ bias,
                      const int* __restrict__ dist, const float* __restrict__ Wg,
                      const float* __restrict__ bg, float* __restrict__ out, int n) {
    constexpr int TOT = H * C;
    constexpr int NI = (TOT + 63) / 64;
    constexpr int ES = 64 / H;
    const int lane = threadIdx.x & 63;
    const int node = blockIdx.x * 4 + (threadIdx.x >> 6);
    if (node >= n) return;

    const int beg = rowptr[node];
    const int deg = rowptr[node + 1] - beg;
    const int hh = lane & (H - 1);
    const int eslot = lane / H;
    const float aldv = ald[(size_t)node * H + hh];

    // ---- phase 1: per-head online max/sum over edges (+ self loop) ----
    float m = -1e30f, s = 0.0f;
    for (int k = eslot; k <= deg; k += ES) {
        int sN = (k < deg) ? csr_src[beg + k] : node;
        float v = lrelu(als[(size_t)sN * H + hh] + aldv);
        float mn = fmaxf(m, v);
        s = s * __expf(m - mn) + __expf(v - mn);
        m = mn;
    }
#pragma unroll
    for (int off = H; off < 64; off <<= 1) {
        float mo = __shfl_xor(m, off);
        float so = __shfl_xor(s, off);
        float M = fmaxf(m, mo);
        s = s * __expf(m - M) + so * __expf(mo - M);
        m = M;
    }
    const float inv = 1.0f / (s + 1e-16f);  // per head hh

    // ---- phase 2: aggregate ----
    float acc[NI];
    int hidx[NI];
#pragma unroll
    for (int q = 0; q < NI; q++) {
        int idx = lane + q * 64;
        acc[q] = 0.0f;
        hidx[q] = ((idx < TOT) ? idx : 0) / C;
    }
    for (int e = 0; e <= deg; e++) {
        const int sN = (e < deg) ? csr_src[beg + e] : node;
        float v = lrelu(als[(size_t)sN * H + hh] + aldv);
        float alpha = __expf(v - m) * inv;  // alpha for head hh (normalized)
        const float* hrow = h + (size_t)sN * TOT;
#pragma unroll
        for (int q = 0; q < NI; q++) {
            int idx = lane + q * 64;
            if (idx < TOT) {
                float aq = (H > 1) ? __shfl(alpha, hidx[q]) : alpha;
                acc[q] += aq * hrow[idx];
            }
        }
    }
    float val[NI];
#pragma unroll
    for (int q = 0; q < NI; q++) {
        int idx = lane + q * 64;
        val[q] = (idx < TOT) ? acc[q] + bias[idx] : 0.0f;
    }

    if (MODE == 1) {  // ELU
#pragma unroll
        for (int q = 0; q < NI; q++) val[q] = val[q] > 0.0f ? val[q] : expm1f(val[q]);
    } else if (MODE == 2) {  // gate (TOT==128)
        float part = val[0] * Wg[lane] + val[1] * Wg[lane + 64];
#pragma unroll
        for (int off = 32; off > 0; off >>= 1) part += __shfl_xor(part, off);
        int d = dist[node];
        float hop = (d <= MAXH) ? (float)d : 0.0f;
        float g = 1.0f / (1.0f + __expf(-(part + hop * Wg[128] + bg[0])));
#pragma unroll
        for (int q = 0; q < NI; q++) val[q] *= g;
    } else if (MODE == 3) {  // log_softmax (TOT==40, NI==1)
        float v = (lane < TOT) ? val[0] : -INFINITY;
        float mm = v;
#pragma unroll
        for (int off = 32; off > 0; off >>= 1) mm = fmaxf(mm, __shfl_xor(mm, off));
        float ex = (lane < TOT) ? __expf(v - mm) : 0.0f;
        float ss = ex;
#pragma unroll
        for (int off = 32; off > 0; off >>= 1) ss += __shfl_xor(ss, off);
        val[0] = v - mm - logf(ss);
    }
#pragma unroll
    for (int q = 0; q < NI; q++) {
        int idx = lane + q * 64;
        if (idx < TOT) out[(size_t)node * TOT + idx] = val[q];
    }
}

static inline int nblk(long long t, int b) { return (int)((t + b - 1) / b); }

extern "C" void kernel_launch(void* const* d_in, const int* in_sizes, int n_in,
                              void* d_out, int out_size, void* d_ws, size_t ws_size,
                              hipStream_t stream) {
    const float* x = (const float*)d_in[0];
    const int* eidx = (const int*)d_in[1];
    const int* seed_mask = (const int*)d_in[2];
    const float* W1 = (const float*)d_in[3];
    const float* a1s = (const float*)d_in[4];
    const float* a1d = (const float*)d_in[5];
    const float* b1 = (const float*)d_in[6];
    const float* W2 = (const float*)d_in[7];
    const float* a2s = (const float*)d_in[8];
    const float* a2d = (const float*)d_in[9];
    const float* b2 = (const float*)d_in[10];
    const float* W3 = (const float*)d_in[11];
    const float* a3s = (const float*)d_in[12];
    const float* a3d = (const float*)d_in[13];
    const float* b3 = (const float*)d_in[14];
    const float* Wg = (const float*)d_in[15];
    const float* bg = (const float*)d_in[16];

    const int n = in_sizes[0] / 128;        // 100000
    const long long E = in_sizes[1] / 2;    // 1600000
    const int E4 = (int)(E / 4);
    const int* src = eidx;
    const int* dst = eidx + E;
    const int4* src4 = (const int4*)src;
    const int4* dst4 = (const int4*)dst;

    char* ws = (char*)d_ws;
    size_t off = 0;
    auto alloc = [&](size_t bytes) -> void* {
        void* p = ws + off;
        off = (off + bytes + 255) & ~(size_t)255;
        return p;
    };
    int* dist    = (int*)alloc((size_t)n * 4);
    int* buf1    = (int*)alloc((size_t)n * 4);      // counts -> cur
    int* buf2    = (int*)alloc((size_t)n * 4);      // tmp(scan)
    u8* reached  = (u8*)alloc((size_t)n);
    u8* nbr      = (u8*)alloc((size_t)n);
    int* rowptr  = (int*)alloc((size_t)(n + 1) * 4);
    int* sums    = (int*)alloc(512 * 4);
    int* boff    = (int*)alloc(512 * 4);
    int* csr_src = (int*)alloc((size_t)E * 4);
    float* als   = (float*)alloc((size_t)n * 8 * 4);
    float* ald   = (float*)alloc((size_t)n * 8 * 4);
    float* bufH  = (float*)alloc((size_t)n * 128 * 4);
    float* bufO  = (float*)alloc((size_t)n * 128 * 4);
    float* out = (float*)d_out;

    const int BS = 256;
    const int nb_scan = nblk(n, 256);

    // ---- BFS hierarchy ----
    k_bfs_init<<<nblk(n, BS), BS, 0, stream>>>(seed_mask, reached, dist, n);
    for (int h = 1; h <= MAXH; h++) {
        hipMemsetAsync(nbr, 0, (size_t)n, stream);
        k_bfs_edge<<<nblk(E4, BS), BS, 0, stream>>>(src4, dst4, reached, nbr, E4);
        k_bfs_node<<<nblk(n, BS), BS, 0, stream>>>(reached, dist, nbr, h, n);
    }

    // ---- CSR build by dst ----
    hipMemsetAsync(buf1, 0, (size_t)n * 4, stream);
    k_count<<<nblk(E4, BS), BS, 0, stream>>>(dst4, buf1, E4);
    k_scan1<<<nb_scan, 256, 0, stream>>>(buf1, buf2, sums, n);
    k_scan2<<<1, 512, 0, stream>>>(sums, boff, nb_scan);
    k_scan3<<<nblk(n, BS), BS, 0, stream>>>(buf2, boff, buf1, rowptr, n);
    k_scatter<<<nblk(E4, BS), BS, 0, stream>>>(src4, dst4, buf1, csr_src, E4);

    // ---- Layer 1: aug(132) -> 8x8, ELU fused ----
    k_gemm_t<128, 132, 64, 64, true, 256><<<nblk(n, 64), 256, 0, stream>>>(x, W1, dist, bufH, n);
    k_attn_t<8, 8><<<nblk(n * 8, BS), BS, 0, stream>>>(bufH, a1s, a1d, als, ald, n);
    k_gat<8, 8, 1><<<nblk(n, 4), 256, 0, stream>>>(rowptr, csr_src, bufH, als, ald, b1,
                                                   nullptr, nullptr, nullptr, bufO, n);

    // ---- Layer 2: 64 -> 8x16, gate fused ----
    k_gemm_t<64, 64, 128, 128, false, 512><<<nblk(n, 64), 512, 0, stream>>>(bufO, W2, nullptr,
                                                                            bufH, n);
    k_attn_t<8, 16><<<nblk(n * 8, BS), BS, 0, stream>>>(bufH, a2s, a2d, als, ald, n);
    k_gat<8, 16, 2><<<nblk(n, 4), 256, 0, stream>>>(rowptr, csr_src, bufH, als, ald, b2,
                                                    dist, Wg, bg, bufO, n);

    // ---- Layer 3: 128 -> 1x40, log_softmax fused ----
    k_gemm_t<128, 128, 64, 40, false, 256><<<nblk(n, 64), 256, 0, stream>>>(bufO, W3, nullptr,
                                                                            bufH, n);
    k_attn_t<1, 40><<<nblk(n, BS), BS, 0, stream>>>(bufH, a3s, a3d, als, ald, n);
    k_gat<1, 40, 3><<<nblk(n, 4), 256, 0, stream>>>(rowptr, csr_src, bufH, als, ald, b3,
                                                    nullptr, nullptr, nullptr, out, n);
}

// Round 5
// 806.885 us; speedup vs baseline: 26.9842x; 1.2448x over previous
//
#include <hip/hip_runtime.h>
#include <hip/hip_bf16.h>
#include <hip/hip_fp16.h>
#include <math.h>

#define MAXH 3
typedef unsigned int u32;
typedef unsigned char u8;

__device__ __forceinline__ float lrelu(float x) { return x > 0.0f ? x : 0.2f * x; }

// ---------------- BFS hierarchy (byte flags, int4 edge loads) ----------------
__global__ void k_bfs_init(const int* __restrict__ seed_mask, u8* reached, int* dist, int n) {
    int i = blockIdx.x * blockDim.x + threadIdx.x;
    if (i < n) {
        int r = (seed_mask[i] == 0);
        reached[i] = (u8)r;
        dist[i] = r ? 0 : (MAXH + 1);
    }
}
__global__ void k_bfs_edge(const int4* __restrict__ src4, const int4* __restrict__ dst4,
                           const u8* __restrict__ reached, u8* nbr, int E4) {
    int i = blockIdx.x * blockDim.x + threadIdx.x;
    if (i < E4) {
        int4 s = src4[i], d = dst4[i];
        if (reached[s.x]) nbr[d.x] = 1;
        if (reached[s.y]) nbr[d.y] = 1;
        if (reached[s.z]) nbr[d.z] = 1;
        if (reached[s.w]) nbr[d.w] = 1;
    }
}
__global__ void k_bfs_node(u8* reached, int* dist, const u8* __restrict__ nbr, int h, int n) {
    int i = blockIdx.x * blockDim.x + threadIdx.x;
    if (i < n) {
        if (nbr[i] && !reached[i]) { dist[i] = h; reached[i] = 1; }
    }
}

// ---------------- CSR build (counting sort by dst) ----------------
__global__ void k_count(const int4* __restrict__ dst4, int* counts, int E4) {
    int i = blockIdx.x * blockDim.x + threadIdx.x;
    if (i < E4) {
        int4 d = dst4[i];
        atomicAdd(&counts[d.x], 1);
        atomicAdd(&counts[d.y], 1);
        atomicAdd(&counts[d.z], 1);
        atomicAdd(&counts[d.w], 1);
    }
}
__global__ void k_scan1(const int* __restrict__ counts, int* tmp, int* sums, int n) {
    __shared__ int sd[256];
    int t = threadIdx.x;
    int i = blockIdx.x * 256 + t;
    int v = (i < n) ? counts[i] : 0;
    sd[t] = v;
    __syncthreads();
    for (int off = 1; off < 256; off <<= 1) {
        int add = (t >= off) ? sd[t - off] : 0;
        __syncthreads();
        sd[t] += add;
        __syncthreads();
    }
    if (i < n) tmp[i] = sd[t];
    if (t == 255) sums[blockIdx.x] = sd[t];
}
__global__ void k_scan2(const int* __restrict__ sums, int* boff, int nb) {
    __shared__ int sd[512];
    int t = threadIdx.x;
    int v = (t < nb) ? sums[t] : 0;
    sd[t] = v;
    __syncthreads();
    for (int off = 1; off < 512; off <<= 1) {
        int add = (t >= off) ? sd[t - off] : 0;
        __syncthreads();
        sd[t] += add;
        __syncthreads();
    }
    if (t < nb) boff[t] = sd[t] - v;  // exclusive
}
__global__ void k_scan3(const int* __restrict__ tmp, const int* __restrict__ boff,
                        int* counts_to_cur, int* rowptr, int n) {
    int i = blockIdx.x * blockDim.x + threadIdx.x;
    if (i < n) {
        int incl = tmp[i] + boff[i >> 8];
        rowptr[i + 1] = incl;
        counts_to_cur[i] = incl - counts_to_cur[i];
        if (i == 0) rowptr[0] = 0;
    }
}
__global__ void k_scatter(const int4* __restrict__ src4, const int4* __restrict__ dst4,
                          int* cur, int* csr_src, int E4) {
    int i = blockIdx.x * blockDim.x + threadIdx.x;
    if (i < E4) {
        int4 s = src4[i], d = dst4[i];
        int p;
        p = atomicAdd(&cur[d.x], 1); csr_src[p] = s.x;
        p = atomicAdd(&cur[d.y], 1); csr_src[p] = s.y;
        p = atomicAdd(&cur[d.z], 1); csr_src[p] = s.z;
        p = atomicAdd(&cur[d.w], 1); csr_src[p] = s.w;
    }
}

// ---------------- register-tiled GEMM, fp16 output ----------------
template <int K, int KW, int MP, int MREAL, bool AUG, int THREADS>
__launch_bounds__(THREADS)
__global__ void k_gemm_t(const float* __restrict__ A, const float* __restrict__ W,
                         const int* __restrict__ dist, __half* __restrict__ out, int n) {
    constexpr int COLT = MP / 4;
    constexpr int ROWT = THREADS / COLT;
    constexpr int RPT = 64 / ROWT;  // = 4
    constexpr int BK = 64;
    constexpr int SAP = BK + 4;
    __shared__ float sA[64 * SAP];
    __shared__ float sW[KW * MP];

    for (int i = threadIdx.x; i < KW * MP; i += THREADS) {
        int r = i / MP, c = i % MP;
        sW[i] = (c < MREAL) ? W[r * MREAL + c] : 0.0f;
    }
    const int tcol = threadIdx.x % COLT;
    const int trow = threadIdx.x / COLT;
    const int rowbase = blockIdx.x * 64;

    float4 acc[RPT];
#pragma unroll
    for (int r = 0; r < RPT; r++) acc[r] = float4{0.f, 0.f, 0.f, 0.f};

    for (int k0 = 0; k0 < K; k0 += BK) {
        __syncthreads();
        for (int i = threadIdx.x; i < 64 * (BK / 4); i += THREADS) {
            int r = i / (BK / 4), c4 = i % (BK / 4);
            int row = rowbase + r;
            float4 v = float4{0.f, 0.f, 0.f, 0.f};
            if (row < n) v = *(const float4*)&A[(size_t)row * K + k0 + c4 * 4];
            *(float4*)&sA[r * SAP + c4 * 4] = v;
        }
        __syncthreads();
#pragma unroll 2
        for (int k4 = 0; k4 < BK / 4; k4++) {
            float4 w0 = *(const float4*)&sW[(k0 + k4 * 4 + 0) * MP + tcol * 4];
            float4 w1 = *(const float4*)&sW[(k0 + k4 * 4 + 1) * MP + tcol * 4];
            float4 w2 = *(const float4*)&sW[(k0 + k4 * 4 + 2) * MP + tcol * 4];
            float4 w3 = *(const float4*)&sW[(k0 + k4 * 4 + 3) * MP + tcol * 4];
#pragma unroll
            for (int r = 0; r < RPT; r++) {
                float4 a = *(const float4*)&sA[(trow * RPT + r) * SAP + k4 * 4];
                acc[r].x += a.x * w0.x + a.y * w1.x + a.z * w2.x + a.w * w3.x;
                acc[r].y += a.x * w0.y + a.y * w1.y + a.z * w2.y + a.w * w3.y;
                acc[r].z += a.x * w0.z + a.y * w1.z + a.z * w2.z + a.w * w3.z;
                acc[r].w += a.x * w0.w + a.y * w1.w + a.z * w2.w + a.w * w3.w;
            }
        }
    }
#pragma unroll
    for (int r = 0; r < RPT; r++) {
        int row = rowbase + trow * RPT + r;
        if (row < n) {
            if (AUG) {
                int d = dist[row];
                if (d <= MAXH) {
                    float4 wd = *(const float4*)&sW[(K + d) * MP + tcol * 4];
                    acc[r].x += wd.x; acc[r].y += wd.y; acc[r].z += wd.z; acc[r].w += wd.w;
                }
            }
            if (tcol * 4 + 3 < MREAL) {
                __half2* op = (__half2*)&out[(size_t)row * MREAL + tcol * 4];
                op[0] = __floats2half2_rn(acc[r].x, acc[r].y);
                op[1] = __floats2half2_rn(acc[r].z, acc[r].w);
            }
        }
    }
}

// ---------------- attention logits (fp16 h) ----------------
template <int H, int C>
__global__ void k_attn_t(const __half* __restrict__ h, const float* __restrict__ a_s,
                         const float* __restrict__ a_d, float* als, float* ald, int n) {
    int i = blockIdx.x * blockDim.x + threadIdx.x;
    if (i < n * H) {
        int hh = i % H;
        const __half2* hp = (const __half2*)(h + (size_t)i * C);
        const float* asp = a_s + hh * C;
        const float* adp = a_d + hh * C;
        float s = 0.0f, d = 0.0f;
#pragma unroll
        for (int c = 0; c < C / 2; c++) {
            float2 v = __half22float2(hp[c]);
            s += v.x * asp[2 * c] + v.y * asp[2 * c + 1];
            d += v.x * adp[2 * c] + v.y * adp[2 * c + 1];
        }
        als[i] = s;
        ald[i] = d;
    }
}

// ---------------- fused GAT layer 1: H=8, C=8 (TOT=64), ELU. 2 edges/iter ---------
__launch_bounds__(256)
__global__ void k_gat1(const int* __restrict__ rowptr, const int* __restrict__ csr_src,
                       const __half* __restrict__ h, const float* __restrict__ als,
                       const float* __restrict__ ald, const float* __restrict__ bias,
                       float* __restrict__ out, int n) {
    const int lane = threadIdx.x & 63;
    const int node = blockIdx.x * 4 + (threadIdx.x >> 6);
    if (node >= n) return;
    const int beg = rowptr[node], deg = rowptr[node + 1] - beg;
    const int hh = lane & 7;
    const float aldv = ald[(size_t)node * 8 + hh];

    float m = -1e30f, s = 0.0f;
    for (int k = lane >> 3; k <= deg; k += 8) {
        int sN = (k < deg) ? csr_src[beg + k] : node;
        float v = lrelu(als[(size_t)sN * 8 + hh] + aldv);
        float mn = fmaxf(m, v);
        s = s * __expf(m - mn) + __expf(v - mn);
        m = mn;
    }
#pragma unroll
    for (int off = 8; off < 64; off <<= 1) {
        float mo = __shfl_xor(m, off), so = __shfl_xor(s, off);
        float M = fmaxf(m, mo);
        s = s * __expf(m - M) + so * __expf(mo - M);
        m = M;
    }
    const float inv = 1.0f / (s + 1e-16f);

    const int half_id = lane >> 5;
    const int l = lane & 31;          // channel pair (2l, 2l+1)
    const int ph = l >> 2;            // head of this pair (C=8)
    const float m_p = __shfl(m, ph);
    const float inv_p = __shfl(inv, ph);
    const float ald_p = __shfl(aldv, ph);
    float ax = 0.0f, ay = 0.0f;
    for (int e = 0; e <= deg; e += 2) {
        int my_e = e + half_id;
        bool valid = my_e <= deg;
        int sN = (my_e < deg) ? csr_src[beg + my_e] : node;
        float v = lrelu(als[(size_t)sN * 8 + ph] + ald_p);
        float alpha = valid ? __expf(v - m_p) * inv_p : 0.0f;
        float2 hf = __half22float2(*(const __half2*)(h + (size_t)sN * 64 + 2 * l));
        ax += alpha * hf.x;
        ay += alpha * hf.y;
    }
    ax += __shfl_xor(ax, 32);
    ay += __shfl_xor(ay, 32);
    if (half_id == 0) {
        float vx = ax + bias[2 * l], vy = ay + bias[2 * l + 1];
        vx = vx > 0.0f ? vx : expm1f(vx);
        vy = vy > 0.0f ? vy : expm1f(vy);
        *(float2*)&out[(size_t)node * 64 + 2 * l] = float2{vx, vy};
    }
}

// ---------------- fused GAT layer 2: H=8, C=16 (TOT=128), gate. 1 edge/iter -------
__launch_bounds__(256)
__global__ void k_gat2(const int* __restrict__ rowptr, const int* __restrict__ csr_src,
                       const __half* __restrict__ h, const float* __restrict__ als,
                       const float* __restrict__ ald, const float* __restrict__ bias,
                       const int* __restrict__ dist, const float* __restrict__ Wg,
                       const float* __restrict__ bg, float* __restrict__ out, int n) {
    const int lane = threadIdx.x & 63;
    const int node = blockIdx.x * 4 + (threadIdx.x >> 6);
    if (node >= n) return;
    const int beg = rowptr[node], deg = rowptr[node + 1] - beg;
    const int hh = lane & 7;
    const float aldv = ald[(size_t)node * 8 + hh];

    float m = -1e30f, s = 0.0f;
    for (int k = lane >> 3; k <= deg; k += 8) {
        int sN = (k < deg) ? csr_src[beg + k] : node;
        float v = lrelu(als[(size_t)sN * 8 + hh] + aldv);
        float mn = fmaxf(m, v);
        s = s * __expf(m - mn) + __expf(v - mn);
        m = mn;
    }
#pragma unroll
    for (int off = 8; off < 64; off <<= 1) {
        float mo = __shfl_xor(m, off), so = __shfl_xor(s, off);
        float M = fmaxf(m, mo);
        s = s * __expf(m - M) + so * __expf(mo - M);
        m = M;
    }
    const float inv = 1.0f / (s + 1e-16f);

    const int ph = lane >> 3;         // head of pair (2*lane)/16
    const float m_p = __shfl(m, ph);
    const float inv_p = __shfl(inv, ph);
    const float ald_p = __shfl(aldv, ph);
    float ax = 0.0f, ay = 0.0f;
    for (int e = 0; e <= deg; e++) {
        int sN = (e < deg) ? csr_src[beg + e] : node;
        float v = lrelu(als[(size_t)sN * 8 + ph] + ald_p);
        float alpha = __expf(v - m_p) * inv_p;
        float2 hf = __half22float2(*(const __half2*)(h + (size_t)sN * 128 + 2 * lane));
        ax += alpha * hf.x;
        ay += alpha * hf.y;
    }
    float vx = ax + bias[2 * lane], vy = ay + bias[2 * lane + 1];
    // gate
    float2 wg = *(const float2*)&Wg[2 * lane];
    float part = vx * wg.x + vy * wg.y;
#pragma unroll
    for (int off = 32; off > 0; off >>= 1) part += __shfl_xor(part, off);
    int d = dist[node];
    float hop = (d <= MAXH) ? (float)d : 0.0f;
    float g = 1.0f / (1.0f + __expf(-(part + hop * Wg[128] + bg[0])));
    *(float2*)&out[(size_t)node * 128 + 2 * lane] = float2{vx * g, vy * g};
}

// ---------------- fused GAT layer 3: H=1, C=40 (TOT=40), log_softmax. 3 edges/iter -
__launch_bounds__(256)
__global__ void k_gat3(const int* __restrict__ rowptr, const int* __restrict__ csr_src,
                       const __half* __restrict__ h, const float* __restrict__ als,
                       const float* __restrict__ ald, const float* __restrict__ bias,
                       float* __restrict__ out, int n) {
    const int lane = threadIdx.x & 63;
    const int node = blockIdx.x * 4 + (threadIdx.x >> 6);
    if (node >= n) return;
    const int beg = rowptr[node], deg = rowptr[node + 1] - beg;
    const float aldv = ald[node];

    float m = -1e30f, s = 0.0f;
    for (int k = lane; k <= deg; k += 64) {
        int sN = (k < deg) ? csr_src[beg + k] : node;
        float v = lrelu(als[sN] + aldv);
        float mn = fmaxf(m, v);
        s = s * __expf(m - mn) + __expf(v - mn);
        m = mn;
    }
#pragma unroll
    for (int off = 1; off < 64; off <<= 1) {
        float mo = __shfl_xor(m, off), so = __shfl_xor(s, off);
        float M = fmaxf(m, mo);
        s = s * __expf(m - M) + so * __expf(mo - M);
        m = M;
    }
    const float inv = 1.0f / (s + 1e-16f);

    const int eg = lane / 20;         // 0,1,2 (lanes 60-63: 3 -> inactive)
    const int p = lane % 20;          // channel pair (2p, 2p+1)
    float ax = 0.0f, ay = 0.0f;
    for (int e = 0; e <= deg; e += 3) {
        int my_e = e + eg;
        bool valid = (eg < 3) && (my_e <= deg);
        int sN = (valid && my_e < deg) ? csr_src[beg + my_e] : node;
        float v = lrelu(als[sN] + aldv);
        float alpha = valid ? __expf(v - m) * inv : 0.0f;
        float2 hf = __half22float2(*(const __half2*)(h + (size_t)sN * 40 + 2 * p));
        ax += alpha * hf.x;
        ay += alpha * hf.y;
    }
    // combine edge groups: lanes p, p+20, p+40 hold the same channel pair
    ax += __shfl(ax, (lane + 20) & 63) + __shfl(ax, (lane + 40) & 63);
    ay += __shfl(ay, (lane + 20) & 63) + __shfl(ay, (lane + 40) & 63);

    float vx = 0.0f, vy = 0.0f, mval = -INFINITY;
    if (lane < 20) {
        vx = ax + bias[2 * p];
        vy = ay + bias[2 * p + 1];
        mval = fmaxf(vx, vy);
    }
#pragma unroll
    for (int off = 16; off > 0; off >>= 1) mval = fmaxf(mval, __shfl_xor(mval, off));
    float ss = (lane < 20) ? __expf(vx - mval) + __expf(vy - mval) : 0.0f;
#pragma unroll
    for (int off = 16; off > 0; off >>= 1) ss += __shfl_xor(ss, off);
    float ls = logf(ss);
    if (lane < 20)
        *(float2*)&out[(size_t)node * 40 + 2 * p] = float2{vx - mval - ls, vy - mval - ls};
}

static inline int nblk(long long t, int b) { return (int)((t + b - 1) / b); }

extern "C" void kernel_launch(void* const* d_in, const int* in_sizes, int n_in,
                              void* d_out, int out_size, void* d_ws, size_t ws_size,
                              hipStream_t stream) {
    const float* x = (const float*)d_in[0];
    const int* eidx = (const int*)d_in[1];
    const int* seed_mask = (const int*)d_in[2];
    const float* W1 = (const float*)d_in[3];
    const float* a1s = (const float*)d_in[4];
    const float* a1d = (const float*)d_in[5];
    const float* b1 = (const float*)d_in[6];
    const float* W2 = (const float*)d_in[7];
    const float* a2s = (const float*)d_in[8];
    const float* a2d = (const float*)d_in[9];
    const float* b2 = (const float*)d_in[10];
    const float* W3 = (const float*)d_in[11];
    const float* a3s = (const float*)d_in[12];
    const float* a3d = (const float*)d_in[13];
    const float* b3 = (const float*)d_in[14];
    const float* Wg = (const float*)d_in[15];
    const float* bg = (const float*)d_in[16];

    const int n = in_sizes[0] / 128;        // 100000
    const long long E = in_sizes[1] / 2;    // 1600000
    const int E4 = (int)(E / 4);
    const int* src = eidx;
    const int* dst = eidx + E;
    const int4* src4 = (const int4*)src;
    const int4* dst4 = (const int4*)dst;

    char* ws = (char*)d_ws;
    size_t off = 0;
    auto alloc = [&](size_t bytes) -> void* {
        void* p = ws + off;
        off = (off + bytes + 255) & ~(size_t)255;
        return p;
    };
    int* dist    = (int*)alloc((size_t)n * 4);
    int* buf1    = (int*)alloc((size_t)n * 4);      // counts -> cur
    int* buf2    = (int*)alloc((size_t)n * 4);      // tmp(scan)
    u8* reached  = (u8*)alloc((size_t)n);
    u8* nbr      = (u8*)alloc((size_t)n);
    int* rowptr  = (int*)alloc((size_t)(n + 1) * 4);
    int* sums    = (int*)alloc(512 * 4);
    int* boff    = (int*)alloc(512 * 4);
    int* csr_src = (int*)alloc((size_t)E * 4);
    float* als   = (float*)alloc((size_t)n * 8 * 4);
    float* ald   = (float*)alloc((size_t)n * 8 * 4);
    __half* bufH = (__half*)alloc((size_t)n * 128 * 2);  // fp16 h (GEMM out)
    float* bufO  = (float*)alloc((size_t)n * 128 * 4);   // fp32 GAT out
    float* out = (float*)d_out;

    const int BS = 256;
    const int nb_scan = nblk(n, 256);

    // ---- BFS hierarchy ----
    k_bfs_init<<<nblk(n, BS), BS, 0, stream>>>(seed_mask, reached, dist, n);
    for (int h = 1; h <= MAXH; h++) {
        hipMemsetAsync(nbr, 0, (size_t)n, stream);
        k_bfs_edge<<<nblk(E4, BS), BS, 0, stream>>>(src4, dst4, reached, nbr, E4);
        k_bfs_node<<<nblk(n, BS), BS, 0, stream>>>(reached, dist, nbr, h, n);
    }

    // ---- CSR build by dst ----
    hipMemsetAsync(buf1, 0, (size_t)n * 4, stream);
    k_count<<<nblk(E4, BS), BS, 0, stream>>>(dst4, buf1, E4);
    k_scan1<<<nb_scan, 256, 0, stream>>>(buf1, buf2, sums, n);
    k_scan2<<<1, 512, 0, stream>>>(sums, boff, nb_scan);
    k_scan3<<<nblk(n, BS), BS, 0, stream>>>(buf2, boff, buf1, rowptr, n);
    k_scatter<<<nblk(E4, BS), BS, 0, stream>>>(src4, dst4, buf1, csr_src, E4);

    // ---- Layer 1: aug(132) -> 8x8, ELU fused ----
    k_gemm_t<128, 132, 64, 64, true, 256><<<nblk(n, 64), 256, 0, stream>>>(x, W1, dist, bufH, n);
    k_attn_t<8, 8><<<nblk(n * 8, BS), BS, 0, stream>>>(bufH, a1s, a1d, als, ald, n);
    k_gat1<<<nblk(n, 4), 256, 0, stream>>>(rowptr, csr_src, bufH, als, ald, b1, bufO, n);

    // ---- Layer 2: 64 -> 8x16, gate fused ----
    k_gemm_t<64, 64, 128, 128, false, 512><<<nblk(n, 64), 512, 0, stream>>>(bufO, W2, nullptr,
                                                                            bufH, n);
    k_attn_t<8, 16><<<nblk(n * 8, BS), BS, 0, stream>>>(bufH, a2s, a2d, als, ald, n);
    k_gat2<<<nblk(n, 4), 256, 0, stream>>>(rowptr, csr_src, bufH, als, ald, b2,
                                           dist, Wg, bg, bufO, n);

    // ---- Layer 3: 128 -> 1x40, log_softmax fused ----
    k_gemm_t<128, 128, 64, 40, false, 256><<<nblk(n, 64), 256, 0, stream>>>(bufO, W3, nullptr,
                                                                            bufH, n);
    k_attn_t<1, 40><<<nblk(n, BS), BS, 0, stream>>>(bufH, a3s, a3d, als, ald, n);
    k_gat3<<<nblk(n, 4), 256, 0, stream>>>(rowptr, csr_src, bufH, als, ald, b3, out, n);
}

// Round 6
// 621.107 us; speedup vs baseline: 35.0555x; 1.2991x over previous
//
#include <hip/hip_runtime.h>
#include <hip/hip_bf16.h>
#include <hip/hip_fp16.h>
#include <math.h>

#define MAXH 3
typedef unsigned int u32;
typedef unsigned char u8;

__device__ __forceinline__ float lrelu(float x) { return x > 0.0f ? x : 0.2f * x; }

// ---------------- BFS hierarchy (CSR in-neighbor scan) ----------------
__global__ void k_bfs_init(const int* __restrict__ seed_mask, u8* reached, int* dist, int n) {
    int i = blockIdx.x * blockDim.x + threadIdx.x;
    if (i < n) {
        int r = (seed_mask[i] == 0);
        reached[i] = (u8)r;
        dist[i] = r ? 0 : (MAXH + 1);
    }
}
__global__ void k_bfs_scan(const int* __restrict__ rowptr, const int* __restrict__ csr_src,
                           const u8* __restrict__ reached, u8* __restrict__ nbr, int n) {
    int i = blockIdx.x * blockDim.x + threadIdx.x;
    if (i < n) {
        if (!reached[i]) {
            int beg = rowptr[i], end = rowptr[i + 1];
            u8 f = 0;
            for (int k = beg; k < end; k++) {
                if (reached[csr_src[k]]) { f = 1; break; }
            }
            nbr[i] = f;
        }
    }
}
__global__ void k_bfs_node(u8* reached, int* dist, const u8* __restrict__ nbr, int h, int n) {
    int i = blockIdx.x * blockDim.x + threadIdx.x;
    if (i < n) {
        if (nbr[i] && !reached[i]) { dist[i] = h; reached[i] = 1; }
    }
}

// ---------------- CSR build (counting sort by dst) ----------------
__global__ void k_count(const int4* __restrict__ dst4, int* counts, int E4) {
    int i = blockIdx.x * blockDim.x + threadIdx.x;
    if (i < E4) {
        int4 d = dst4[i];
        atomicAdd(&counts[d.x], 1);
        atomicAdd(&counts[d.y], 1);
        atomicAdd(&counts[d.z], 1);
        atomicAdd(&counts[d.w], 1);
    }
}
__global__ void k_scan1(const int* __restrict__ counts, int* tmp, int* sums, int n) {
    __shared__ int sd[256];
    int t = threadIdx.x;
    int i = blockIdx.x * 256 + t;
    int v = (i < n) ? counts[i] : 0;
    sd[t] = v;
    __syncthreads();
    for (int off = 1; off < 256; off <<= 1) {
        int add = (t >= off) ? sd[t - off] : 0;
        __syncthreads();
        sd[t] += add;
        __syncthreads();
    }
    if (i < n) tmp[i] = sd[t];
    if (t == 255) sums[blockIdx.x] = sd[t];
}
__global__ void k_scan2(const int* __restrict__ sums, int* boff, int nb) {
    __shared__ int sd[512];
    int t = threadIdx.x;
    int v = (t < nb) ? sums[t] : 0;
    sd[t] = v;
    __syncthreads();
    for (int off = 1; off < 512; off <<= 1) {
        int add = (t >= off) ? sd[t - off] : 0;
        __syncthreads();
        sd[t] += add;
        __syncthreads();
    }
    if (t < nb) boff[t] = sd[t] - v;  // exclusive
}
__global__ void k_scan3(const int* __restrict__ tmp, const int* __restrict__ boff,
                        int* counts_to_cur, int* rowptr, int n) {
    int i = blockIdx.x * blockDim.x + threadIdx.x;
    if (i < n) {
        int incl = tmp[i] + boff[i >> 8];
        rowptr[i + 1] = incl;
        counts_to_cur[i] = incl - counts_to_cur[i];
        if (i == 0) rowptr[0] = 0;
    }
}
__global__ void k_scatter(const int4* __restrict__ src4, const int4* __restrict__ dst4,
                          int* cur, int* csr_src, int E4) {
    int i = blockIdx.x * blockDim.x + threadIdx.x;
    if (i < E4) {
        int4 s = src4[i], d = dst4[i];
        int p;
        p = atomicAdd(&cur[d.x], 1); csr_src[p] = s.x;
        p = atomicAdd(&cur[d.y], 1); csr_src[p] = s.y;
        p = atomicAdd(&cur[d.z], 1); csr_src[p] = s.z;
        p = atomicAdd(&cur[d.w], 1); csr_src[p] = s.w;
    }
}

// ---------------- register-tiled GEMM, fp16 output ----------------
template <int K, int KW, int MP, int MREAL, bool AUG, int THREADS>
__launch_bounds__(THREADS)
__global__ void k_gemm_t(const float* __restrict__ A, const float* __restrict__ W,
                         const int* __restrict__ dist, __half* __restrict__ out, int n) {
    constexpr int COLT = MP / 4;
    constexpr int ROWT = THREADS / COLT;
    constexpr int RPT = 64 / ROWT;  // = 4
    constexpr int BK = 64;
    constexpr int SAP = BK + 4;
    __shared__ float sA[64 * SAP];
    __shared__ float sW[KW * MP];

    for (int i = threadIdx.x; i < KW * MP; i += THREADS) {
        int r = i / MP, c = i % MP;
        sW[i] = (c < MREAL) ? W[r * MREAL + c] : 0.0f;
    }
    const int tcol = threadIdx.x % COLT;
    const int trow = threadIdx.x / COLT;
    const int rowbase = blockIdx.x * 64;

    float4 acc[RPT];
#pragma unroll
    for (int r = 0; r < RPT; r++) acc[r] = float4{0.f, 0.f, 0.f, 0.f};

    for (int k0 = 0; k0 < K; k0 += BK) {
        __syncthreads();
        for (int i = threadIdx.x; i < 64 * (BK / 4); i += THREADS) {
            int r = i / (BK / 4), c4 = i % (BK / 4);
            int row = rowbase + r;
            float4 v = float4{0.f, 0.f, 0.f, 0.f};
            if (row < n) v = *(const float4*)&A[(size_t)row * K + k0 + c4 * 4];
            *(float4*)&sA[r * SAP + c4 * 4] = v;
        }
        __syncthreads();
#pragma unroll 2
        for (int k4 = 0; k4 < BK / 4; k4++) {
            float4 w0 = *(const float4*)&sW[(k0 + k4 * 4 + 0) * MP + tcol * 4];
            float4 w1 = *(const float4*)&sW[(k0 + k4 * 4 + 1) * MP + tcol * 4];
            float4 w2 = *(const float4*)&sW[(k0 + k4 * 4 + 2) * MP + tcol * 4];
            float4 w3 = *(const float4*)&sW[(k0 + k4 * 4 + 3) * MP + tcol * 4];
#pragma unroll
            for (int r = 0; r < RPT; r++) {
                float4 a = *(const float4*)&sA[(trow * RPT + r) * SAP + k4 * 4];
                acc[r].x += a.x * w0.x + a.y * w1.x + a.z * w2.x + a.w * w3.x;
                acc[r].y += a.x * w0.y + a.y * w1.y + a.z * w2.y + a.w * w3.y;
                acc[r].z += a.x * w0.z + a.y * w1.z + a.z * w2.z + a.w * w3.z;
                acc[r].w += a.x * w0.w + a.y * w1.w + a.z * w2.w + a.w * w3.w;
            }
        }
    }
#pragma unroll
    for (int r = 0; r < RPT; r++) {
        int row = rowbase + trow * RPT + r;
        if (row < n) {
            if (AUG) {
                int d = dist[row];
                if (d <= MAXH) {
                    float4 wd = *(const float4*)&sW[(K + d) * MP + tcol * 4];
                    acc[r].x += wd.x; acc[r].y += wd.y; acc[r].z += wd.z; acc[r].w += wd.w;
                }
            }
            if (tcol * 4 + 3 < MREAL) {
                __half2* op = (__half2*)&out[(size_t)row * MREAL + tcol * 4];
                op[0] = __floats2half2_rn(acc[r].x, acc[r].y);
                op[1] = __floats2half2_rn(acc[r].z, acc[r].w);
            }
        }
    }
}

// ---------------- attention logits (fp16 h) ----------------
template <int H, int C>
__global__ void k_attn_t(const __half* __restrict__ h, const float* __restrict__ a_s,
                         const float* __restrict__ a_d, float* als, float* ald, int n) {
    int i = blockIdx.x * blockDim.x + threadIdx.x;
    if (i < n * H) {
        int hh = i % H;
        const __half2* hp = (const __half2*)(h + (size_t)i * C);
        const float* asp = a_s + hh * C;
        const float* adp = a_d + hh * C;
        float s = 0.0f, d = 0.0f;
#pragma unroll
        for (int c = 0; c < C / 2; c++) {
            float2 v = __half22float2(hp[c]);
            s += v.x * asp[2 * c] + v.y * asp[2 * c + 1];
            d += v.x * adp[2 * c] + v.y * adp[2 * c + 1];
        }
        als[i] = s;
        ald[i] = d;
    }
}

// ---------------- fused GAT: single-pass no-max softmax, readlane edge broadcast ----
// CH channels per lane (1 float or 1 half2 pair); NL = TOT/CH active lanes.
// self-loop folded into init (s=1, acc=h[node]); m0 = self logit as stabilizer.
// MODE: 1=ELU, 2=gate, 3=log_softmax
template <int H, int C, int CH, int MODE>
__launch_bounds__(256)
__global__ void k_gat(const int* __restrict__ rowptr, const int* __restrict__ csr_src,
                      const __half* __restrict__ h, const float* __restrict__ als,
                      const float* __restrict__ ald, const float* __restrict__ bias,
                      const int* __restrict__ dist, const float* __restrict__ Wg,
                      const float* __restrict__ bg, float* __restrict__ out, int n) {
    constexpr int TOT = H * C;
    constexpr int NL = TOT / CH;
    const int lane = threadIdx.x & 63;
    const int node = blockIdx.x * 4 + (threadIdx.x >> 6);
    if (node >= n) return;
    const int beg = rowptr[node];
    const int deg = rowptr[node + 1] - beg;

    const int cl = (lane < NL) ? lane : 0;
    const int hd = (cl * CH) / C;
    const float ald_hd = ald[(size_t)node * H + hd];
    const float m0 = lrelu(als[(size_t)node * H + hd] + ald_hd);

    float s = 1.0f, ax, ay = 0.0f;
    if (CH == 2) {
        float2 hv = __half22float2(*(const __half2*)(h + (size_t)node * TOT + cl * 2));
        ax = hv.x; ay = hv.y;
    } else {
        ax = __half2float(h[(size_t)node * TOT + cl]);
    }

    for (int base = 0; base < deg; base += 64) {
        const int myE = base + lane;
        int sReg = (myE < deg) ? csr_src[beg + myE] : 0;
        const int cnt = min(64, deg - base);
        int e = 0;
        for (; e + 2 <= cnt; e += 2) {
            const int s0 = __builtin_amdgcn_readlane(sReg, e);
            const int s1 = __builtin_amdgcn_readlane(sReg, e + 1);
            const float v0 = lrelu(als[(size_t)s0 * H + hd] + ald_hd);
            const float v1 = lrelu(als[(size_t)s1 * H + hd] + ald_hd);
            const float p0 = __expf(v0 - m0);
            const float p1 = __expf(v1 - m0);
            if (CH == 2) {
                float2 h0 = __half22float2(*(const __half2*)(h + (size_t)s0 * TOT + cl * 2));
                float2 h1 = __half22float2(*(const __half2*)(h + (size_t)s1 * TOT + cl * 2));
                ax += p0 * h0.x + p1 * h1.x;
                ay += p0 * h0.y + p1 * h1.y;
            } else {
                ax += p0 * __half2float(h[(size_t)s0 * TOT + cl])
                    + p1 * __half2float(h[(size_t)s1 * TOT + cl]);
            }
            s += p0 + p1;
        }
        if (e < cnt) {
            const int s0 = __builtin_amdgcn_readlane(sReg, e);
            const float v0 = lrelu(als[(size_t)s0 * H + hd] + ald_hd);
            const float p0 = __expf(v0 - m0);
            if (CH == 2) {
                float2 h0 = __half22float2(*(const __half2*)(h + (size_t)s0 * TOT + cl * 2));
                ax += p0 * h0.x; ay += p0 * h0.y;
            } else {
                ax += p0 * __half2float(h[(size_t)s0 * TOT + cl]);
            }
            s += p0;
        }
    }

    const float inv = 1.0f / (s + 1e-16f);
    float vx = ax * inv + bias[cl * CH];
    float vy = (CH == 2) ? (ay * inv + bias[cl * CH + 1]) : 0.0f;

    if (MODE == 1) {  // ELU (CH=1, NL=64)
        vx = vx > 0.0f ? vx : expm1f(vx);
        out[(size_t)node * TOT + cl] = vx;
    } else if (MODE == 2) {  // gate (CH=2, NL=64)
        float2 wg = *(const float2*)&Wg[cl * 2];
        float part = vx * wg.x + vy * wg.y;
#pragma unroll
        for (int off = 32; off > 0; off >>= 1) part += __shfl_xor(part, off);
        int d = dist[node];
        float hop = (d <= MAXH) ? (float)d : 0.0f;
        float g = 1.0f / (1.0f + __expf(-(part + hop * Wg[128] + bg[0])));
        *(float2*)&out[(size_t)node * TOT + cl * 2] = float2{vx * g, vy * g};
    } else if (MODE == 3) {  // log_softmax (CH=1, NL=40)
        float v = (lane < NL) ? vx : -INFINITY;
        float mm = v;
#pragma unroll
        for (int off = 32; off > 0; off >>= 1) mm = fmaxf(mm, __shfl_xor(mm, off));
        float ex = (lane < NL) ? __expf(v - mm) : 0.0f;
        float ss = ex;
#pragma unroll
        for (int off = 32; off > 0; off >>= 1) ss += __shfl_xor(ss, off);
        float ls = logf(ss);
        if (lane < NL) out[(size_t)node * TOT + cl] = v - mm - ls;
    }
}

static inline int nblk(long long t, int b) { return (int)((t + b - 1) / b); }

extern "C" void kernel_launch(void* const* d_in, const int* in_sizes, int n_in,
                              void* d_out, int out_size, void* d_ws, size_t ws_size,
                              hipStream_t stream) {
    const float* x = (const float*)d_in[0];
    const int* eidx = (const int*)d_in[1];
    const int* seed_mask = (const int*)d_in[2];
    const float* W1 = (const float*)d_in[3];
    const float* a1s = (const float*)d_in[4];
    const float* a1d = (const float*)d_in[5];
    const float* b1 = (const float*)d_in[6];
    const float* W2 = (const float*)d_in[7];
    const float* a2s = (const float*)d_in[8];
    const float* a2d = (const float*)d_in[9];
    const float* b2 = (const float*)d_in[10];
    const float* W3 = (const float*)d_in[11];
    const float* a3s = (const float*)d_in[12];
    const float* a3d = (const float*)d_in[13];
    const float* b3 = (const float*)d_in[14];
    const float* Wg = (const float*)d_in[15];
    const float* bg = (const float*)d_in[16];

    const int n = in_sizes[0] / 128;        // 100000
    const long long E = in_sizes[1] / 2;    // 1600000
    const int E4 = (int)(E / 4);
    const int* src = eidx;
    const int* dst = eidx + E;
    const int4* src4 = (const int4*)src;
    const int4* dst4 = (const int4*)dst;

    char* ws = (char*)d_ws;
    size_t off = 0;
    auto alloc = [&](size_t bytes) -> void* {
        void* p = ws + off;
        off = (off + bytes + 255) & ~(size_t)255;
        return p;
    };
    int* dist    = (int*)alloc((size_t)n * 4);
    int* buf1    = (int*)alloc((size_t)n * 4);      // counts -> cur
    int* buf2    = (int*)alloc((size_t)n * 4);      // tmp(scan)
    u8* reached  = (u8*)alloc((size_t)n);
    u8* nbr      = (u8*)alloc((size_t)n);
    int* rowptr  = (int*)alloc((size_t)(n + 1) * 4);
    int* sums    = (int*)alloc(512 * 4);
    int* boff    = (int*)alloc(512 * 4);
    int* csr_src = (int*)alloc((size_t)E * 4);
    float* als   = (float*)alloc((size_t)n * 8 * 4);
    float* ald   = (float*)alloc((size_t)n * 8 * 4);
    __half* bufH = (__half*)alloc((size_t)n * 128 * 2);  // fp16 h (GEMM out)
    float* bufO  = (float*)alloc((size_t)n * 128 * 4);   // fp32 GAT out
    float* out = (float*)d_out;

    const int BS = 256;
    const int nb_scan = nblk(n, 256);

    // ---- CSR build by dst (needed by BFS too) ----
    hipMemsetAsync(buf1, 0, (size_t)n * 4, stream);
    k_bfs_init<<<nblk(n, BS), BS, 0, stream>>>(seed_mask, reached, dist, n);
    k_count<<<nblk(E4, BS), BS, 0, stream>>>(dst4, buf1, E4);
    k_scan1<<<nb_scan, 256, 0, stream>>>(buf1, buf2, sums, n);
    k_scan2<<<1, 512, 0, stream>>>(sums, boff, nb_scan);
    k_scan3<<<nblk(n, BS), BS, 0, stream>>>(buf2, boff, buf1, rowptr, n);
    k_scatter<<<nblk(E4, BS), BS, 0, stream>>>(src4, dst4, buf1, csr_src, E4);

    // ---- BFS hierarchy via CSR ----
    for (int h = 1; h <= MAXH; h++) {
        k_bfs_scan<<<nblk(n, BS), BS, 0, stream>>>(rowptr, csr_src, reached, nbr, n);
        k_bfs_node<<<nblk(n, BS), BS, 0, stream>>>(reached, dist, nbr, h, n);
    }

    // ---- Layer 1: aug(132) -> 8x8, ELU fused ----
    k_gemm_t<128, 132, 64, 64, true, 256><<<nblk(n, 64), 256, 0, stream>>>(x, W1, dist, bufH, n);
    k_attn_t<8, 8><<<nblk(n * 8, BS), BS, 0, stream>>>(bufH, a1s, a1d, als, ald, n);
    k_gat<8, 8, 1, 1><<<nblk(n, 4), 256, 0, stream>>>(rowptr, csr_src, bufH, als, ald, b1,
                                                      nullptr, nullptr, nullptr, bufO, n);

    // ---- Layer 2: 64 -> 8x16, gate fused ----
    k_gemm_t<64, 64, 128, 128, false, 512><<<nblk(n, 64), 512, 0, stream>>>(bufO, W2, nullptr,
                                                                            bufH, n);
    k_attn_t<8, 16><<<nblk(n * 8, BS), BS, 0, stream>>>(bufH, a2s, a2d, als, ald, n);
    k_gat<8, 16, 2, 2><<<nblk(n, 4), 256, 0, stream>>>(rowptr, csr_src, bufH, als, ald, b2,
                                                       dist, Wg, bg, bufO, n);

    // ---- Layer 3: 128 -> 1x40, log_softmax fused ----
    k_gemm_t<128, 128, 64, 40, false, 256><<<nblk(n, 64), 256, 0, stream>>>(bufO, W3, nullptr,
                                                                            bufH, n);
    k_attn_t<1, 40><<<nblk(n, BS), BS, 0, stream>>>(bufH, a3s, a3d, als, ald, n);
    k_gat<1, 40, 1, 3><<<nblk(n, 4), 256, 0, stream>>>(rowptr, csr_src, bufH, als, ald, b3,
                                                       nullptr, nullptr, nullptr, out, n);
}

// Round 7
// 510.892 us; speedup vs baseline: 42.6180x; 1.2157x over previous
//
#include <hip/hip_runtime.h>
#include <hip/hip_bf16.h>
#include <hip/hip_fp16.h>
#include <math.h>

#define MAXH 3
#define NSB 9              // 512 nodes per bin
#define NS (1 << NSB)
#define SRCBITS 17         // n < 131072
#define SRCMASK ((1 << SRCBITS) - 1)
typedef unsigned int u32;
typedef unsigned char u8;

__device__ __forceinline__ float lrelu(float x) { return x > 0.0f ? x : 0.2f * x; }

// ---------------- BFS hierarchy (CSR in-neighbor scan) ----------------
__global__ void k_bfs_init(const int* __restrict__ seed_mask, u8* reached, int* dist, int n) {
    int i = blockIdx.x * blockDim.x + threadIdx.x;
    if (i < n) {
        int r = (seed_mask[i] == 0);
        reached[i] = (u8)r;
        dist[i] = r ? 0 : (MAXH + 1);
    }
}
__global__ void k_bfs_scan(const int* __restrict__ rowptr, const int* __restrict__ csr_src,
                           const u8* __restrict__ reached, u8* __restrict__ nbr, int n) {
    int i = blockIdx.x * blockDim.x + threadIdx.x;
    if (i < n) {
        if (!reached[i]) {
            int beg = rowptr[i], end = rowptr[i + 1];
            u8 f = 0;
            for (int k = beg; k < end; k++) {
                if (reached[csr_src[k]]) { f = 1; break; }
            }
            nbr[i] = f;
        }
    }
}
__global__ void k_bfs_node(u8* reached, int* dist, const u8* __restrict__ nbr, int h, int n) {
    int i = blockIdx.x * blockDim.x + threadIdx.x;
    if (i < n) {
        if (nbr[i] && !reached[i]) { dist[i] = h; reached[i] = 1; }
    }
}

// ---------------- CSR build: locality-binned 2-level counting sort ----------------
__global__ void k_bincount(const int4* __restrict__ dst4, int* bincnt, int E4) {
    __shared__ int cnt[256];
    int t = threadIdx.x;
    cnt[t] = 0;
    __syncthreads();
    int i = blockIdx.x * 256 + t;
    if (i < E4) {
        int4 d = dst4[i];
        atomicAdd(&cnt[d.x >> NSB], 1);
        atomicAdd(&cnt[d.y >> NSB], 1);
        atomicAdd(&cnt[d.z >> NSB], 1);
        atomicAdd(&cnt[d.w >> NSB], 1);
    }
    __syncthreads();
    if (cnt[t] > 0) atomicAdd(&bincnt[t], cnt[t]);
}

__global__ void k_binscan(const int* __restrict__ bincnt, int* binbase, int* bincur,
                          int* rowptr, int BINS, int E, int n) {
    __shared__ int sd[256];
    int t = threadIdx.x;
    int v = (t < BINS) ? bincnt[t] : 0;
    sd[t] = v;
    __syncthreads();
    for (int off = 1; off < 256; off <<= 1) {
        int add = (t >= off) ? sd[t - off] : 0;
        __syncthreads();
        sd[t] += add;
        __syncthreads();
    }
    int excl = sd[t] - v;
    if (t < BINS) { binbase[t] = excl; bincur[t] = excl; }
    if (t == 0) { binbase[BINS] = E; rowptr[n] = E; }
}

// multisplit: per-block LDS count+rank, one global reservation per (block,bin)
__global__ void k_binscatter(const int4* __restrict__ src4, const int4* __restrict__ dst4,
                             int* bincur, int* __restrict__ pairs, int E4, int BINS) {
    __shared__ int cnt[256], base[256];
    int t = threadIdx.x;
    cnt[t] = 0;
    __syncthreads();
    int i = blockIdx.x * 256 + t;
    int bin[4], rank[4], pack[4];
    bool valid = i < E4;
    if (valid) {
        int4 s = src4[i], d = dst4[i];
        bin[0] = d.x >> NSB; pack[0] = ((d.x & (NS - 1)) << SRCBITS) | s.x;
        bin[1] = d.y >> NSB; pack[1] = ((d.y & (NS - 1)) << SRCBITS) | s.y;
        bin[2] = d.z >> NSB; pack[2] = ((d.z & (NS - 1)) << SRCBITS) | s.z;
        bin[3] = d.w >> NSB; pack[3] = ((d.w & (NS - 1)) << SRCBITS) | s.w;
        rank[0] = atomicAdd(&cnt[bin[0]], 1);
        rank[1] = atomicAdd(&cnt[bin[1]], 1);
        rank[2] = atomicAdd(&cnt[bin[2]], 1);
        rank[3] = atomicAdd(&cnt[bin[3]], 1);
    }
    __syncthreads();
    if (t < BINS && cnt[t] > 0) base[t] = atomicAdd(&bincur[t], cnt[t]);
    __syncthreads();
    if (valid) {
        pairs[base[bin[0]] + rank[0]] = pack[0];
        pairs[base[bin[1]] + rank[1]] = pack[1];
        pairs[base[bin[2]] + rank[2]] = pack[2];
        pairs[base[bin[3]] + rank[3]] = pack[3];
    }
}

// one workgroup per bin: LDS hist -> Blelloch scan -> rowptr + placement (LDS atomics)
__global__ void k_binsort(const int* __restrict__ pairs, const int* __restrict__ binbase,
                          int* __restrict__ rowptr, int* __restrict__ csr_src, int n) {
    __shared__ int hist[NS];
    const int b = blockIdx.x, t = threadIdx.x;
    const int nbeg = b << NSB;
    const int ebeg = binbase[b];
    const int ecnt = binbase[b + 1] - ebeg;
    hist[t] = 0; hist[t + 256] = 0;
    __syncthreads();
    for (int i = t; i < ecnt; i += 256)
        atomicAdd(&hist[(u32)pairs[ebeg + i] >> SRCBITS], 1);
    // Blelloch exclusive scan over NS=512
    for (int d = 1; d < NS; d <<= 1) {
        __syncthreads();
        int idx = (t + 1) * (d << 1) - 1;
        if (idx < NS) hist[idx] += hist[idx - d];
    }
    __syncthreads();
    if (t == 0) hist[NS - 1] = 0;
    for (int d = NS / 2; d >= 1; d >>= 1) {
        __syncthreads();
        int idx = (t + 1) * (d << 1) - 1;
        if (idx < NS) { int tmp = hist[idx - d]; hist[idx - d] = hist[idx]; hist[idx] += tmp; }
    }
    __syncthreads();
    int g0 = nbeg + t, g1 = nbeg + t + 256;
    if (g0 < n) rowptr[g0] = ebeg + hist[t];
    if (g1 < n) rowptr[g1] = ebeg + hist[t + 256];
    __syncthreads();
    for (int i = t; i < ecnt; i += 256) {
        int p = pairs[ebeg + i];
        int pos = atomicAdd(&hist[(u32)p >> SRCBITS], 1);
        csr_src[ebeg + pos] = p & SRCMASK;
    }
}

// ---------------- register-tiled GEMM, fp16 output ----------------
template <int K, int KW, int MP, int MREAL, bool AUG, int THREADS>
__launch_bounds__(THREADS)
__global__ void k_gemm_t(const float* __restrict__ A, const float* __restrict__ W,
                         const int* __restrict__ dist, __half* __restrict__ out, int n) {
    constexpr int COLT = MP / 4;
    constexpr int ROWT = THREADS / COLT;
    constexpr int RPT = 64 / ROWT;  // = 4
    constexpr int BK = 64;
    constexpr int SAP = BK + 4;
    __shared__ float sA[64 * SAP];
    __shared__ float sW[KW * MP];

    for (int i = threadIdx.x; i < KW * MP; i += THREADS) {
        int r = i / MP, c = i % MP;
        sW[i] = (c < MREAL) ? W[r * MREAL + c] : 0.0f;
    }
    const int tcol = threadIdx.x % COLT;
    const int trow = threadIdx.x / COLT;
    const int rowbase = blockIdx.x * 64;

    float4 acc[RPT];
#pragma unroll
    for (int r = 0; r < RPT; r++) acc[r] = float4{0.f, 0.f, 0.f, 0.f};

    for (int k0 = 0; k0 < K; k0 += BK) {
        __syncthreads();
        for (int i = threadIdx.x; i < 64 * (BK / 4); i += THREADS) {
            int r = i / (BK / 4), c4 = i % (BK / 4);
            int row = rowbase + r;
            float4 v = float4{0.f, 0.f, 0.f, 0.f};
            if (row < n) v = *(const float4*)&A[(size_t)row * K + k0 + c4 * 4];
            *(float4*)&sA[r * SAP + c4 * 4] = v;
        }
        __syncthreads();
#pragma unroll 2
        for (int k4 = 0; k4 < BK / 4; k4++) {
            float4 w0 = *(const float4*)&sW[(k0 + k4 * 4 + 0) * MP + tcol * 4];
            float4 w1 = *(const float4*)&sW[(k0 + k4 * 4 + 1) * MP + tcol * 4];
            float4 w2 = *(const float4*)&sW[(k0 + k4 * 4 + 2) * MP + tcol * 4];
            float4 w3 = *(const float4*)&sW[(k0 + k4 * 4 + 3) * MP + tcol * 4];
#pragma unroll
            for (int r = 0; r < RPT; r++) {
                float4 a = *(const float4*)&sA[(trow * RPT + r) * SAP + k4 * 4];
                acc[r].x += a.x * w0.x + a.y * w1.x + a.z * w2.x + a.w * w3.x;
                acc[r].y += a.x * w0.y + a.y * w1.y + a.z * w2.y + a.w * w3.y;
                acc[r].z += a.x * w0.z + a.y * w1.z + a.z * w2.z + a.w * w3.z;
                acc[r].w += a.x * w0.w + a.y * w1.w + a.z * w2.w + a.w * w3.w;
            }
        }
    }
#pragma unroll
    for (int r = 0; r < RPT; r++) {
        int row = rowbase + trow * RPT + r;
        if (row < n) {
            if (AUG) {
                int d = dist[row];
                if (d <= MAXH) {
                    float4 wd = *(const float4*)&sW[(K + d) * MP + tcol * 4];
                    acc[r].x += wd.x; acc[r].y += wd.y; acc[r].z += wd.z; acc[r].w += wd.w;
                }
            }
            if (tcol * 4 + 3 < MREAL) {
                __half2* op = (__half2*)&out[(size_t)row * MREAL + tcol * 4];
                op[0] = __floats2half2_rn(acc[r].x, acc[r].y);
                op[1] = __floats2half2_rn(acc[r].z, acc[r].w);
            }
        }
    }
}

// ---------------- attention logits (fp16 h) ----------------
template <int H, int C>
__global__ void k_attn_t(const __half* __restrict__ h, const float* __restrict__ a_s,
                         const float* __restrict__ a_d, float* als, float* ald, int n) {
    int i = blockIdx.x * blockDim.x + threadIdx.x;
    if (i < n * H) {
        int hh = i % H;
        const __half2* hp = (const __half2*)(h + (size_t)i * C);
        const float* asp = a_s + hh * C;
        const float* adp = a_d + hh * C;
        float s = 0.0f, d = 0.0f;
#pragma unroll
        for (int c = 0; c < C / 2; c++) {
            float2 v = __half22float2(hp[c]);
            s += v.x * asp[2 * c] + v.y * asp[2 * c + 1];
            d += v.x * adp[2 * c] + v.y * adp[2 * c + 1];
        }
        als[i] = s;
        ald[i] = d;
    }
}

// ---------------- fused GAT: single-pass no-max softmax, readlane edge broadcast ----
template <int H, int C, int CH, int MODE>
__launch_bounds__(256)
__global__ void k_gat(const int* __restrict__ rowptr, const int* __restrict__ csr_src,
                      const __half* __restrict__ h, const float* __restrict__ als,
                      const float* __restrict__ ald, const float* __restrict__ bias,
                      const int* __restrict__ dist, const float* __restrict__ Wg,
                      const float* __restrict__ bg, float* __restrict__ out, int n) {
    constexpr int TOT = H * C;
    constexpr int NL = TOT / CH;
    const int lane = threadIdx.x & 63;
    const int node = blockIdx.x * 4 + (threadIdx.x >> 6);
    if (node >= n) return;
    const int beg = rowptr[node];
    const int deg = rowptr[node + 1] - beg;

    const int cl = (lane < NL) ? lane : 0;
    const int hd = (cl * CH) / C;
    const float ald_hd = ald[(size_t)node * H + hd];
    const float m0 = lrelu(als[(size_t)node * H + hd] + ald_hd);

    float s = 1.0f, ax, ay = 0.0f;
    if (CH == 2) {
        float2 hv = __half22float2(*(const __half2*)(h + (size_t)node * TOT + cl * 2));
        ax = hv.x; ay = hv.y;
    } else {
        ax = __half2float(h[(size_t)node * TOT + cl]);
    }

    for (int base = 0; base < deg; base += 64) {
        const int myE = base + lane;
        int sReg = (myE < deg) ? csr_src[beg + myE] : 0;
        const int cnt = min(64, deg - base);
        int e = 0;
        for (; e + 2 <= cnt; e += 2) {
            const int s0 = __builtin_amdgcn_readlane(sReg, e);
            const int s1 = __builtin_amdgcn_readlane(sReg, e + 1);
            const float v0 = lrelu(als[(size_t)s0 * H + hd] + ald_hd);
            const float v1 = lrelu(als[(size_t)s1 * H + hd] + ald_hd);
            const float p0 = __expf(v0 - m0);
            const float p1 = __expf(v1 - m0);
            if (CH == 2) {
                float2 h0 = __half22float2(*(const __half2*)(h + (size_t)s0 * TOT + cl * 2));
                float2 h1 = __half22float2(*(const __half2*)(h + (size_t)s1 * TOT + cl * 2));
                ax += p0 * h0.x + p1 * h1.x;
                ay += p0 * h0.y + p1 * h1.y;
            } else {
                ax += p0 * __half2float(h[(size_t)s0 * TOT + cl])
                    + p1 * __half2float(h[(size_t)s1 * TOT + cl]);
            }
            s += p0 + p1;
        }
        if (e < cnt) {
            const int s0 = __builtin_amdgcn_readlane(sReg, e);
            const float v0 = lrelu(als[(size_t)s0 * H + hd] + ald_hd);
            const float p0 = __expf(v0 - m0);
            if (CH == 2) {
                float2 h0 = __half22float2(*(const __half2*)(h + (size_t)s0 * TOT + cl * 2));
                ax += p0 * h0.x; ay += p0 * h0.y;
            } else {
                ax += p0 * __half2float(h[(size_t)s0 * TOT + cl]);
            }
            s += p0;
        }
    }

    const float inv = 1.0f / (s + 1e-16f);
    float vx = ax * inv + bias[cl * CH];
    float vy = (CH == 2) ? (ay * inv + bias[cl * CH + 1]) : 0.0f;

    if (MODE == 1) {  // ELU (CH=1, NL=64)
        vx = vx > 0.0f ? vx : expm1f(vx);
        out[(size_t)node * TOT + cl] = vx;
    } else if (MODE == 2) {  // gate (CH=2, NL=64)
        float2 wg = *(const float2*)&Wg[cl * 2];
        float part = vx * wg.x + vy * wg.y;
#pragma unroll
        for (int off = 32; off > 0; off >>= 1) part += __shfl_xor(part, off);
        int d = dist[node];
        float hop = (d <= MAXH) ? (float)d : 0.0f;
        float g = 1.0f / (1.0f + __expf(-(part + hop * Wg[128] + bg[0])));
        *(float2*)&out[(size_t)node * TOT + cl * 2] = float2{vx * g, vy * g};
    } else if (MODE == 3) {  // log_softmax (CH=1, NL=40)
        float v = (lane < NL) ? vx : -INFINITY;
        float mm = v;
#pragma unroll
        for (int off = 32; off > 0; off >>= 1) mm = fmaxf(mm, __shfl_xor(mm, off));
        float ex = (lane < NL) ? __expf(v - mm) : 0.0f;
        float ss = ex;
#pragma unroll
        for (int off = 32; off > 0; off >>= 1) ss += __shfl_xor(ss, off);
        float ls = logf(ss);
        if (lane < NL) out[(size_t)node * TOT + cl] = v - mm - ls;
    }
}

static inline int nblk(long long t, int b) { return (int)((t + b - 1) / b); }

extern "C" void kernel_launch(void* const* d_in, const int* in_sizes, int n_in,
                              void* d_out, int out_size, void* d_ws, size_t ws_size,
                              hipStream_t stream) {
    const float* x = (const float*)d_in[0];
    const int* eidx = (const int*)d_in[1];
    const int* seed_mask = (const int*)d_in[2];
    const float* W1 = (const float*)d_in[3];
    const float* a1s = (const float*)d_in[4];
    const float* a1d = (const float*)d_in[5];
    const float* b1 = (const float*)d_in[6];
    const float* W2 = (const float*)d_in[7];
    const float* a2s = (const float*)d_in[8];
    const float* a2d = (const float*)d_in[9];
    const float* b2 = (const float*)d_in[10];
    const float* W3 = (const float*)d_in[11];
    const float* a3s = (const float*)d_in[12];
    const float* a3d = (const float*)d_in[13];
    const float* b3 = (const float*)d_in[14];
    const float* Wg = (const float*)d_in[15];
    const float* bg = (const float*)d_in[16];

    const int n = in_sizes[0] / 128;        // 100000
    const long long E = in_sizes[1] / 2;    // 1600000
    const int E4 = (int)(E / 4);
    const int* src = eidx;
    const int* dst = eidx + E;
    const int4* src4 = (const int4*)src;
    const int4* dst4 = (const int4*)dst;
    const int BINS = (n + NS - 1) >> NSB;   // 196 <= 256

    char* ws = (char*)d_ws;
    size_t off = 0;
    auto alloc = [&](size_t bytes) -> void* {
        void* p = ws + off;
        off = (off + bytes + 255) & ~(size_t)255;
        return p;
    };
    int* dist    = (int*)alloc((size_t)n * 4);
    u8* reached  = (u8*)alloc((size_t)n);
    u8* nbr      = (u8*)alloc((size_t)n);
    int* rowptr  = (int*)alloc((size_t)(n + 1) * 4);
    int* bincnt  = (int*)alloc(256 * 4);
    int* binbase = (int*)alloc(257 * 4);
    int* bincur  = (int*)alloc(256 * 4);
    int* csr_src = (int*)alloc((size_t)E * 4);
    float* als   = (float*)alloc((size_t)n * 8 * 4);
    float* ald   = (float*)alloc((size_t)n * 8 * 4);
    __half* bufH = (__half*)alloc((size_t)n * 128 * 2);  // fp16 h (GEMM out)
    float* bufO  = (float*)alloc((size_t)n * 128 * 4);   // fp32 GAT out
    int* pairs   = (int*)bufO;  // alias: pairs only live during CSR build
    float* out = (float*)d_out;

    const int BS = 256;

    // ---- CSR build: binned counting sort ----
    hipMemsetAsync(bincnt, 0, 256 * 4, stream);
    k_bfs_init<<<nblk(n, BS), BS, 0, stream>>>(seed_mask, reached, dist, n);
    k_bincount<<<nblk(E4, BS), BS, 0, stream>>>(dst4, bincnt, E4);
    k_binscan<<<1, 256, 0, stream>>>(bincnt, binbase, bincur, rowptr, BINS, (int)E, n);
    k_binscatter<<<nblk(E4, BS), BS, 0, stream>>>(src4, dst4, bincur, pairs, E4, BINS);
    k_binsort<<<BINS, 256, 0, stream>>>(pairs, binbase, rowptr, csr_src, n);

    // ---- BFS hierarchy via CSR ----
    for (int h = 1; h <= MAXH; h++) {
        k_bfs_scan<<<nblk(n, BS), BS, 0, stream>>>(rowptr, csr_src, reached, nbr, n);
        k_bfs_node<<<nblk(n, BS), BS, 0, stream>>>(reached, dist, nbr, h, n);
    }

    // ---- Layer 1: aug(132) -> 8x8, ELU fused ----
    k_gemm_t<128, 132, 64, 64, true, 256><<<nblk(n, 64), 256, 0, stream>>>(x, W1, dist, bufH, n);
    k_attn_t<8, 8><<<nblk(n * 8, BS), BS, 0, stream>>>(bufH, a1s, a1d, als, ald, n);
    k_gat<8, 8, 1, 1><<<nblk(n, 4), 256, 0, stream>>>(rowptr, csr_src, bufH, als, ald, b1,
                                                      nullptr, nullptr, nullptr, bufO, n);

    // ---- Layer 2: 64 -> 8x16, gate fused ----
    k_gemm_t<64, 64, 128, 128, false, 512><<<nblk(n, 64), 512, 0, stream>>>(bufO, W2, nullptr,
                                                                            bufH, n);
    k_attn_t<8, 16><<<nblk(n * 8, BS), BS, 0, stream>>>(bufH, a2s, a2d, als, ald, n);
    k_gat<8, 16, 2, 2><<<nblk(n, 4), 256, 0, stream>>>(rowptr, csr_src, bufH, als, ald, b2,
                                                       dist, Wg, bg, bufO, n);

    // ---- Layer 3: 128 -> 1x40, log_softmax fused ----
    k_gemm_t<128, 128, 64, 40, false, 256><<<nblk(n, 64), 256, 0, stream>>>(bufO, W3, nullptr,
                                                                            bufH, n);
    k_attn_t<1, 40><<<nblk(n, BS), BS, 0, stream>>>(bufH, a3s, a3d, als, ald, n);
    k_gat<1, 40, 1, 3><<<nblk(n, 4), 256, 0, stream>>>(rowptr, csr_src, bufH, als, ald, b3,
                                                       nullptr, nullptr, nullptr, out, n);
}

// Round 8
// 469.242 us; speedup vs baseline: 46.4007x; 1.0888x over previous
//
#include <hip/hip_runtime.h>
#include <hip/hip_bf16.h>
#include <hip/hip_fp16.h>
#include <math.h>

#define MAXH 3
#define NSB 9              // 512 nodes per bin
#define NS (1 << NSB)
#define SRCBITS 17         // n < 131072
#define SRCMASK ((1 << SRCBITS) - 1)
#define LOG2E 1.4426950408889634f
typedef unsigned int u32;
typedef unsigned char u8;

__device__ __forceinline__ float lrelu2(float x) { return fmaxf(x, 0.2f * x); }
__device__ __forceinline__ float fexp2(float x) {
#if __has_builtin(__builtin_amdgcn_exp2f)
    return __builtin_amdgcn_exp2f(x);
#else
    return exp2f(x);
#endif
}

// ---------------- BFS hierarchy (CSR in-neighbor scan) ----------------
__global__ void k_bfs_init(const int* __restrict__ seed_mask, u8* reached, int* dist, int n) {
    int i = blockIdx.x * blockDim.x + threadIdx.x;
    if (i < n) {
        int r = (seed_mask[i] == 0);
        reached[i] = (u8)r;
        dist[i] = r ? 0 : (MAXH + 1);
    }
}
__global__ void k_bfs_scan(const int* __restrict__ rowptr, const int* __restrict__ csr_src,
                           const u8* __restrict__ reached, u8* __restrict__ nbr, int n) {
    int i = blockIdx.x * blockDim.x + threadIdx.x;
    if (i < n) {
        if (!reached[i]) {
            int beg = rowptr[i], end = rowptr[i + 1];
            u8 f = 0;
            for (int k = beg; k < end; k++) {
                if (reached[csr_src[k]]) { f = 1; break; }
            }
            nbr[i] = f;
        }
    }
}
__global__ void k_bfs_node(u8* reached, int* dist, const u8* __restrict__ nbr, int h, int n) {
    int i = blockIdx.x * blockDim.x + threadIdx.x;
    if (i < n) {
        if (nbr[i] && !reached[i]) { dist[i] = h; reached[i] = 1; }
    }
}

// ---------------- CSR build: locality-binned 2-level counting sort ----------------
__global__ void k_bincount(const int4* __restrict__ dst4, int* bincnt, int E4) {
    __shared__ int cnt[256];
    int t = threadIdx.x;
    cnt[t] = 0;
    __syncthreads();
    int i = blockIdx.x * 256 + t;
    if (i < E4) {
        int4 d = dst4[i];
        atomicAdd(&cnt[d.x >> NSB], 1);
        atomicAdd(&cnt[d.y >> NSB], 1);
        atomicAdd(&cnt[d.z >> NSB], 1);
        atomicAdd(&cnt[d.w >> NSB], 1);
    }
    __syncthreads();
    if (cnt[t] > 0) atomicAdd(&bincnt[t], cnt[t]);
}

__global__ void k_binscan(const int* __restrict__ bincnt, int* binbase, int* bincur,
                          int* rowptr, int BINS, int E, int n) {
    __shared__ int sd[256];
    int t = threadIdx.x;
    int v = (t < BINS) ? bincnt[t] : 0;
    sd[t] = v;
    __syncthreads();
    for (int off = 1; off < 256; off <<= 1) {
        int add = (t >= off) ? sd[t - off] : 0;
        __syncthreads();
        sd[t] += add;
        __syncthreads();
    }
    int excl = sd[t] - v;
    if (t < BINS) { binbase[t] = excl; bincur[t] = excl; }
    if (t == 0) { binbase[BINS] = E; rowptr[n] = E; }
}

// multisplit: per-block LDS count+rank, one global reservation per (block,bin)
__global__ void k_binscatter(const int4* __restrict__ src4, const int4* __restrict__ dst4,
                             int* bincur, int* __restrict__ pairs, int E4, int BINS) {
    __shared__ int cnt[256], base[256];
    int t = threadIdx.x;
    cnt[t] = 0;
    __syncthreads();
    int i = blockIdx.x * 256 + t;
    int bin[4], rank[4], pack[4];
    bool valid = i < E4;
    if (valid) {
        int4 s = src4[i], d = dst4[i];
        bin[0] = d.x >> NSB; pack[0] = ((d.x & (NS - 1)) << SRCBITS) | s.x;
        bin[1] = d.y >> NSB; pack[1] = ((d.y & (NS - 1)) << SRCBITS) | s.y;
        bin[2] = d.z >> NSB; pack[2] = ((d.z & (NS - 1)) << SRCBITS) | s.z;
        bin[3] = d.w >> NSB; pack[3] = ((d.w & (NS - 1)) << SRCBITS) | s.w;
        rank[0] = atomicAdd(&cnt[bin[0]], 1);
        rank[1] = atomicAdd(&cnt[bin[1]], 1);
        rank[2] = atomicAdd(&cnt[bin[2]], 1);
        rank[3] = atomicAdd(&cnt[bin[3]], 1);
    }
    __syncthreads();
    if (t < BINS && cnt[t] > 0) base[t] = atomicAdd(&bincur[t], cnt[t]);
    __syncthreads();
    if (valid) {
        pairs[base[bin[0]] + rank[0]] = pack[0];
        pairs[base[bin[1]] + rank[1]] = pack[1];
        pairs[base[bin[2]] + rank[2]] = pack[2];
        pairs[base[bin[3]] + rank[3]] = pack[3];
    }
}

// one workgroup per bin: LDS hist -> Blelloch scan -> rowptr + placement (LDS atomics)
__global__ void k_binsort(const int* __restrict__ pairs, const int* __restrict__ binbase,
                          int* __restrict__ rowptr, int* __restrict__ csr_src, int n) {
    __shared__ int hist[NS];
    const int b = blockIdx.x, t = threadIdx.x;
    const int nbeg = b << NSB;
    const int ebeg = binbase[b];
    const int ecnt = binbase[b + 1] - ebeg;
    hist[t] = 0; hist[t + 256] = 0;
    __syncthreads();
    for (int i = t; i < ecnt; i += 256)
        atomicAdd(&hist[(u32)pairs[ebeg + i] >> SRCBITS], 1);
    for (int d = 1; d < NS; d <<= 1) {
        __syncthreads();
        int idx = (t + 1) * (d << 1) - 1;
        if (idx < NS) hist[idx] += hist[idx - d];
    }
    __syncthreads();
    if (t == 0) hist[NS - 1] = 0;
    for (int d = NS / 2; d >= 1; d >>= 1) {
        __syncthreads();
        int idx = (t + 1) * (d << 1) - 1;
        if (idx < NS) { int tmp = hist[idx - d]; hist[idx - d] = hist[idx]; hist[idx] += tmp; }
    }
    __syncthreads();
    int g0 = nbeg + t, g1 = nbeg + t + 256;
    if (g0 < n) rowptr[g0] = ebeg + hist[t];
    if (g1 < n) rowptr[g1] = ebeg + hist[t + 256];
    __syncthreads();
    for (int i = t; i < ecnt; i += 256) {
        int p = pairs[ebeg + i];
        int pos = atomicAdd(&hist[(u32)p >> SRCBITS], 1);
        csr_src[ebeg + pos] = p & SRCMASK;
    }
}

// ---------------- register-tiled GEMM, fp16 out, fused attention logits ----------------
// A: float or __half. Attn: als/ald[row,H] = (h . a_s/a_d) * LOG2E via in-register
// partial dots + shfl reduce over the tcols covering each head.
template <typename AT, int K, int KW, int MP, int MREAL, bool AUG, int AH, int AC, int THREADS>
__launch_bounds__(THREADS)
__global__ void k_gemm_t(const AT* __restrict__ A, const float* __restrict__ W,
                         const float* __restrict__ a_s, const float* __restrict__ a_d,
                         const int* __restrict__ dist, __half* __restrict__ out,
                         float* __restrict__ als, float* __restrict__ ald, int n) {
    constexpr int COLT = MP / 4;
    constexpr int ROWT = THREADS / COLT;
    constexpr int RPT = 64 / ROWT;  // = 4
    constexpr int BK = 64;
    constexpr int SAP = BK + 4;
    __shared__ float sA[64 * SAP];
    __shared__ float sW[KW * MP];

    for (int i = threadIdx.x; i < KW * MP; i += THREADS) {
        int r = i / MP, c = i % MP;
        sW[i] = (c < MREAL) ? W[r * MREAL + c] : 0.0f;
    }
    const int tcol = threadIdx.x % COLT;
    const int trow = threadIdx.x / COLT;
    const int rowbase = blockIdx.x * 64;

    float4 acc[RPT];
#pragma unroll
    for (int r = 0; r < RPT; r++) acc[r] = float4{0.f, 0.f, 0.f, 0.f};

    for (int k0 = 0; k0 < K; k0 += BK) {
        __syncthreads();
        if constexpr (sizeof(AT) == 4) {
            for (int i = threadIdx.x; i < 64 * (BK / 4); i += THREADS) {
                int r = i / (BK / 4), c4 = i % (BK / 4);
                int row = rowbase + r;
                float4 v = float4{0.f, 0.f, 0.f, 0.f};
                if (row < n) v = *(const float4*)&A[(size_t)row * K + k0 + c4 * 4];
                *(float4*)&sA[r * SAP + c4 * 4] = v;
            }
        } else {
            for (int i = threadIdx.x; i < 64 * (BK / 8); i += THREADS) {
                int r = i / (BK / 8), c8 = i % (BK / 8);
                int row = rowbase + r;
                float f[8];
#pragma unroll
                for (int j = 0; j < 8; j++) f[j] = 0.0f;
                if (row < n) {
                    int4 raw = *(const int4*)&A[(size_t)row * K + k0 + c8 * 8];
                    float2 p0 = __half22float2(*(const __half2*)&raw.x);
                    float2 p1 = __half22float2(*(const __half2*)&raw.y);
                    float2 p2 = __half22float2(*(const __half2*)&raw.z);
                    float2 p3 = __half22float2(*(const __half2*)&raw.w);
                    f[0] = p0.x; f[1] = p0.y; f[2] = p1.x; f[3] = p1.y;
                    f[4] = p2.x; f[5] = p2.y; f[6] = p3.x; f[7] = p3.y;
                }
#pragma unroll
                for (int j = 0; j < 8; j++) sA[r * SAP + c8 * 8 + j] = f[j];
            }
        }
        __syncthreads();
#pragma unroll 2
        for (int k4 = 0; k4 < BK / 4; k4++) {
            float4 w0 = *(const float4*)&sW[(k0 + k4 * 4 + 0) * MP + tcol * 4];
            float4 w1 = *(const float4*)&sW[(k0 + k4 * 4 + 1) * MP + tcol * 4];
            float4 w2 = *(const float4*)&sW[(k0 + k4 * 4 + 2) * MP + tcol * 4];
            float4 w3 = *(const float4*)&sW[(k0 + k4 * 4 + 3) * MP + tcol * 4];
#pragma unroll
            for (int r = 0; r < RPT; r++) {
                float4 a = *(const float4*)&sA[(trow * RPT + r) * SAP + k4 * 4];
                acc[r].x += a.x * w0.x + a.y * w1.x + a.z * w2.x + a.w * w3.x;
                acc[r].y += a.x * w0.y + a.y * w1.y + a.z * w2.y + a.w * w3.y;
                acc[r].z += a.x * w0.z + a.y * w1.z + a.z * w2.z + a.w * w3.z;
                acc[r].w += a.x * w0.w + a.y * w1.w + a.z * w2.w + a.w * w3.w;
            }
        }
    }

    // attn weight slice for this thread's 4 cols (pre-scaled by log2 e)
    float as_[4], ad_[4];
#pragma unroll
    for (int j = 0; j < 4; j++) {
        int col = tcol * 4 + j;
        bool ok = col < MREAL;
        as_[j] = ok ? a_s[col] * LOG2E : 0.0f;
        ad_[j] = ok ? a_d[col] * LOG2E : 0.0f;
    }
    constexpr int TPH = AC / 4;
    constexpr int RW = (TPH & (TPH - 1)) ? 16 : TPH;  // shuffle-reduce width
    const int head = (tcol * 4) / AC;

#pragma unroll
    for (int r = 0; r < RPT; r++) {
        int row = rowbase + trow * RPT + r;
        if (AUG && row < n) {
            int d = dist[row];
            if (d <= MAXH) {
                float4 wd = *(const float4*)&sW[(K + d) * MP + tcol * 4];
                acc[r].x += wd.x; acc[r].y += wd.y; acc[r].z += wd.z; acc[r].w += wd.w;
            }
        }
        float ps = acc[r].x * as_[0] + acc[r].y * as_[1] + acc[r].z * as_[2] + acc[r].w * as_[3];
        float pd = acc[r].x * ad_[0] + acc[r].y * ad_[1] + acc[r].z * ad_[2] + acc[r].w * ad_[3];
#pragma unroll
        for (int o = 1; o < RW; o <<= 1) {
            ps += __shfl_xor(ps, o);
            pd += __shfl_xor(pd, o);
        }
        if (row < n) {
            if ((tcol % RW) == 0) {
                als[(size_t)row * AH + head] = ps;
                ald[(size_t)row * AH + head] = pd;
            }
            if (tcol * 4 + 3 < MREAL) {
                __half2* op = (__half2*)&out[(size_t)row * MREAL + tcol * 4];
                op[0] = __floats2half2_rn(acc[r].x, acc[r].y);
                op[1] = __floats2half2_rn(acc[r].z, acc[r].w);
            }
        }
    }
}

// ---------------- fused GAT: single-pass no-max softmax (exp2 domain) ----------------
// MODE: 1=ELU (OT=half), 2=gate (OT=half), 3=log_softmax (OT=float)
template <int H, int C, int CH, int MODE, typename OT>
__launch_bounds__(256)
__global__ void k_gat(const int* __restrict__ rowptr, const int* __restrict__ csr_src,
                      const __half* __restrict__ h, const float* __restrict__ als,
                      const float* __restrict__ ald, const float* __restrict__ bias,
                      const int* __restrict__ dist, const float* __restrict__ Wg,
                      const float* __restrict__ bg, OT* __restrict__ out, int n) {
    constexpr int TOT = H * C;
    constexpr int NL = TOT / CH;
    const int lane = threadIdx.x & 63;
    const int node = blockIdx.x * 4 + (threadIdx.x >> 6);
    if (node >= n) return;
    const int beg = rowptr[node];
    const int deg = rowptr[node + 1] - beg;

    const int cl = (lane < NL) ? lane : 0;
    const int hd = (cl * CH) / C;
    const float ald_hd = ald[(size_t)node * H + hd];
    const float m0 = lrelu2(als[(size_t)node * H + hd] + ald_hd);

    float s = 1.0f, ax, ay = 0.0f;
    if (CH == 2) {
        float2 hv = __half22float2(*(const __half2*)(h + (size_t)node * TOT + cl * 2));
        ax = hv.x; ay = hv.y;
    } else {
        ax = __half2float(h[(size_t)node * TOT + cl]);
    }

    auto body = [&](int sN) {
        float t = als[(size_t)sN * H + hd] + ald_hd;
        float p = fexp2(lrelu2(t) - m0);
        s += p;
        if (CH == 2) {
            float2 hf = __half22float2(*(const __half2*)(h + (size_t)sN * TOT + cl * 2));
            ax += p * hf.x;
            ay += p * hf.y;
        } else {
            ax += p * __half2float(h[(size_t)sN * TOT + cl]);
        }
    };

    for (int base = 0; base < deg; base += 64) {
        const int myE = base + lane;
        int sReg = (myE < deg) ? csr_src[beg + myE] : 0;
        const int cnt = min(64, deg - base);
        int e = 0;
        for (; e + 4 <= cnt; e += 4) {
            body(__builtin_amdgcn_readlane(sReg, e));
            body(__builtin_amdgcn_readlane(sReg, e + 1));
            body(__builtin_amdgcn_readlane(sReg, e + 2));
            body(__builtin_amdgcn_readlane(sReg, e + 3));
        }
        for (; e < cnt; e++) body(__builtin_amdgcn_readlane(sReg, e));
    }

    const float inv = 1.0f / (s + 1e-16f);
    float vx = ax * inv + bias[cl * CH];
    float vy = (CH == 2) ? (ay * inv + bias[cl * CH + 1]) : 0.0f;

    if (MODE == 1) {  // ELU -> fp16
        vx = vx > 0.0f ? vx : expm1f(vx);
        ((__half*)out)[(size_t)node * TOT + cl] = __float2half(vx);
    } else if (MODE == 2) {  // gate -> fp16
        float2 wg = *(const float2*)&Wg[cl * 2];
        float part = vx * wg.x + vy * wg.y;
#pragma unroll
        for (int off = 32; off > 0; off >>= 1) part += __shfl_xor(part, off);
        int d = dist[node];
        float hop = (d <= MAXH) ? (float)d : 0.0f;
        float g = 1.0f / (1.0f + __expf(-(part + hop * Wg[128] + bg[0])));
        *(__half2*)&((__half*)out)[(size_t)node * TOT + cl * 2] =
            __floats2half2_rn(vx * g, vy * g);
    } else if (MODE == 3) {  // log_softmax -> fp32
        float v = (lane < NL) ? vx : -INFINITY;
        float mm = v;
#pragma unroll
        for (int off = 32; off > 0; off >>= 1) mm = fmaxf(mm, __shfl_xor(mm, off));
        float ex = (lane < NL) ? __expf(v - mm) : 0.0f;
        float ss = ex;
#pragma unroll
        for (int off = 32; off > 0; off >>= 1) ss += __shfl_xor(ss, off);
        float ls = logf(ss);
        if (lane < NL) ((float*)out)[(size_t)node * TOT + cl] = v - mm - ls;
    }
}

static inline int nblk(long long t, int b) { return (int)((t + b - 1) / b); }

extern "C" void kernel_launch(void* const* d_in, const int* in_sizes, int n_in,
                              void* d_out, int out_size, void* d_ws, size_t ws_size,
                              hipStream_t stream) {
    const float* x = (const float*)d_in[0];
    const int* eidx = (const int*)d_in[1];
    const int* seed_mask = (const int*)d_in[2];
    const float* W1 = (const float*)d_in[3];
    const float* a1s = (const float*)d_in[4];
    const float* a1d = (const float*)d_in[5];
    const float* b1 = (const float*)d_in[6];
    const float* W2 = (const float*)d_in[7];
    const float* a2s = (const float*)d_in[8];
    const float* a2d = (const float*)d_in[9];
    const float* b2 = (const float*)d_in[10];
    const float* W3 = (const float*)d_in[11];
    const float* a3s = (const float*)d_in[12];
    const float* a3d = (const float*)d_in[13];
    const float* b3 = (const float*)d_in[14];
    const float* Wg = (const float*)d_in[15];
    const float* bg = (const float*)d_in[16];

    const int n = in_sizes[0] / 128;        // 100000
    const long long E = in_sizes[1] / 2;    // 1600000
    const int E4 = (int)(E / 4);
    const int4* src4 = (const int4*)eidx;
    const int4* dst4 = (const int4*)(eidx + E);
    const int BINS = (n + NS - 1) >> NSB;   // 196 <= 256

    char* ws = (char*)d_ws;
    size_t off = 0;
    auto alloc = [&](size_t bytes) -> void* {
        void* p = ws + off;
        off = (off + bytes + 255) & ~(size_t)255;
        return p;
    };
    int* dist    = (int*)alloc((size_t)n * 4);
    u8* reached  = (u8*)alloc((size_t)n);
    u8* nbr      = (u8*)alloc((size_t)n);
    int* rowptr  = (int*)alloc((size_t)(n + 1) * 4);
    int* bincnt  = (int*)alloc(256 * 4);
    int* binbase = (int*)alloc(257 * 4);
    int* bincur  = (int*)alloc(256 * 4);
    int* csr_src = (int*)alloc((size_t)E * 4);
    float* als   = (float*)alloc((size_t)n * 8 * 4);
    float* ald   = (float*)alloc((size_t)n * 8 * 4);
    __half* hbuf = (__half*)alloc((size_t)n * 128 * 2);  // GEMM out (h)
    __half* abuf = (__half*)alloc((size_t)n * 128 * 2);  // GAT out (next A)
    int* pairs   = (int*)abuf;  // alias: pairs only live during CSR build
    float* out = (float*)d_out;

    const int BS = 256;

    // ---- CSR build: binned counting sort ----
    hipMemsetAsync(bincnt, 0, 256 * 4, stream);
    k_bfs_init<<<nblk(n, BS), BS, 0, stream>>>(seed_mask, reached, dist, n);
    k_bincount<<<nblk(E4, BS), BS, 0, stream>>>(dst4, bincnt, E4);
    k_binscan<<<1, 256, 0, stream>>>(bincnt, binbase, bincur, rowptr, BINS, (int)E, n);
    k_binscatter<<<nblk(E4, BS), BS, 0, stream>>>(src4, dst4, bincur, pairs, E4, BINS);
    k_binsort<<<BINS, 256, 0, stream>>>(pairs, binbase, rowptr, csr_src, n);

    // ---- BFS hierarchy via CSR ----
    for (int h = 1; h <= MAXH; h++) {
        k_bfs_scan<<<nblk(n, BS), BS, 0, stream>>>(rowptr, csr_src, reached, nbr, n);
        k_bfs_node<<<nblk(n, BS), BS, 0, stream>>>(reached, dist, nbr, h, n);
    }

    // ---- Layer 1: aug(132) -> 8x8, ELU fused ----
    k_gemm_t<float, 128, 132, 64, 64, true, 8, 8, 256>
        <<<nblk(n, 64), 256, 0, stream>>>(x, W1, a1s, a1d, dist, hbuf, als, ald, n);
    k_gat<8, 8, 1, 1, __half><<<nblk(n, 4), 256, 0, stream>>>(
        rowptr, csr_src, hbuf, als, ald, b1, nullptr, nullptr, nullptr, abuf, n);

    // ---- Layer 2: 64 -> 8x16, gate fused ----
    k_gemm_t<__half, 64, 64, 128, 128, false, 8, 16, 512>
        <<<nblk(n, 64), 512, 0, stream>>>(abuf, W2, a2s, a2d, nullptr, hbuf, als, ald, n);
    k_gat<8, 16, 2, 2, __half><<<nblk(n, 4), 256, 0, stream>>>(
        rowptr, csr_src, hbuf, als, ald, b2, dist, Wg, bg, abuf, n);

    // ---- Layer 3: 128 -> 1x40, log_softmax fused ----
    k_gemm_t<__half, 128, 128, 64, 40, false, 1, 40, 256>
        <<<nblk(n, 64), 256, 0, stream>>>(abuf, W3, a3s, a3d, nullptr, hbuf, als, ald, n);
    k_gat<1, 40, 1, 3, float><<<nblk(n, 4), 256, 0, stream>>>(
        rowptr, csr_src, hbuf, als, ald, b3, nullptr, nullptr, nullptr, out, n);
}